// Round 1
// baseline (513.974 us; speedup 1.0000x reference)
//
#include <hip/hip_runtime.h>
#include <hip/hip_bf16.h>

#define D_IN   512
#define D_H1   256
#define D_C1A  128
#define D_Z     64
#define D_C2A  128
#define D_C2B  256
#define D_OUT  512

__device__ __forceinline__ float leaky_f(float x) { return x >= 0.f ? x : 0.01f * x; }

// ---------------- CSR build ----------------
__global__ void zero_i32(int* __restrict__ p, int n) {
    int i = blockIdx.x * blockDim.x + threadIdx.x;
    if (i < n) p[i] = 0;
}

__global__ void hist_kernel(const int* __restrict__ rows, int* __restrict__ counts, int E) {
    int i = blockIdx.x * blockDim.x + threadIdx.x;
    if (i < E) atomicAdd(&counts[rows[i]], 1);
}

__global__ __launch_bounds__(1024)
void scan_kernel(const int* __restrict__ counts, int* __restrict__ starts,
                 int* __restrict__ cursor, int n) {
    __shared__ int buf[1024];
    __shared__ int base_s;
    int tid = threadIdx.x;
    if (tid == 0) base_s = 0;
    __syncthreads();
    for (int c0 = 0; c0 < n; c0 += 1024) {
        int i = c0 + tid;
        int v = (i < n) ? counts[i] : 0;
        buf[tid] = v;
        __syncthreads();
        for (int off = 1; off < 1024; off <<= 1) {
            int t = (tid >= off) ? buf[tid - off] : 0;
            __syncthreads();
            buf[tid] += t;
            __syncthreads();
        }
        int incl = buf[tid];
        int base = base_s;
        __syncthreads();
        if (i < n) { int ex = base + incl - v; starts[i] = ex; cursor[i] = ex; }
        if (tid == 1023) base_s = base + buf[1023];
        __syncthreads();
    }
    if (tid == 0) starts[n] = base_s;
}

__global__ void scatter_kernel(const int* __restrict__ rows, int* __restrict__ cursor,
                               int* __restrict__ eidx, int E) {
    int i = blockIdx.x * blockDim.x + threadIdx.x;
    if (i < E) {
        int pos = atomicAdd(&cursor[rows[i]], 1);
        eidx[pos] = i;
    }
}

// ---------------- SpMM: h = leaky( A_sp @ C1 + b1 ), D_H1 = 256 cols ----------------
__global__ __launch_bounds__(64)
void spmm_leaky_kernel(const int* __restrict__ starts, const int* __restrict__ eidx,
                       const int* __restrict__ cols, const float* __restrict__ vals,
                       const float* __restrict__ C1, const float* __restrict__ b1,
                       float* __restrict__ h) {
    int r = blockIdx.x;
    int t = threadIdx.x;               // 0..63 -> 4 cols each (256 total)
    const float4* C1v = (const float4*)C1;
    float4 acc = ((const float4*)b1)[t];
    int s = starts[r], e = starts[r + 1];
    for (int p = s; p < e; ++p) {
        int ei = eidx[p];
        int c = cols[ei];
        float v = vals[ei];
        float4 src = C1v[(size_t)c * 64 + t];
        acc.x += v * src.x; acc.y += v * src.y;
        acc.z += v * src.z; acc.w += v * src.w;
    }
    acc.x = leaky_f(acc.x); acc.y = leaky_f(acc.y);
    acc.z = leaky_f(acc.z); acc.w = leaky_f(acc.w);
    ((float4*)h)[(size_t)r * 64 + t] = acc;
}

// ---------------- Generic tiled f32 GEMM: C = act(A@B + bias) ----------------
// BM=128, BN=64, BK=16; 256 threads; each thread 8x4 micro-tile.
template<int ACT>
__global__ __launch_bounds__(256)
void gemm_f32(const float* __restrict__ A, const float* __restrict__ B,
              const float* __restrict__ bias, float* __restrict__ C,
              int M, int N, int K) {
    __shared__ float sA[16][128 + 4];
    __shared__ float sB[16][64 + 4];
    const int bm = blockIdx.x * 128;
    const int bn = blockIdx.y * 64;
    const int tid = threadIdx.x;
    const int tr = tid >> 4;   // 0..15
    const int tc = tid & 15;   // 0..15

    float acc[8][4];
#pragma unroll
    for (int i = 0; i < 8; i++)
#pragma unroll
        for (int j = 0; j < 4; j++) acc[i][j] = 0.f;

    for (int k0 = 0; k0 < K; k0 += 16) {
        // A tile: 128x16 -> sA[kk][m]
#pragma unroll
        for (int it = 0; it < 8; ++it) {
            int m = (tid >> 4) + (it << 4);
            int kk = tid & 15;
            int gm = bm + m;
            sA[kk][m] = (gm < M) ? A[(size_t)gm * K + k0 + kk] : 0.f;
        }
        // B tile: 16x64 -> sB[kk][n]
#pragma unroll
        for (int it = 0; it < 4; ++it) {
            int kk = (tid >> 6) + (it << 2);
            int n = tid & 63;
            sB[kk][n] = B[(size_t)(k0 + kk) * N + bn + n];
        }
        __syncthreads();
#pragma unroll
        for (int kk = 0; kk < 16; ++kk) {
            float a[8], b[4];
#pragma unroll
            for (int i = 0; i < 8; i++) a[i] = sA[kk][tr * 8 + i];
#pragma unroll
            for (int j = 0; j < 4; j++) b[j] = sB[kk][tc * 4 + j];
#pragma unroll
            for (int i = 0; i < 8; i++)
#pragma unroll
                for (int j = 0; j < 4; j++) acc[i][j] += a[i] * b[j];
        }
        __syncthreads();
    }

#pragma unroll
    for (int i = 0; i < 8; i++) {
        int gm = bm + tr * 8 + i;
        if (gm >= M) continue;
#pragma unroll
        for (int j = 0; j < 4; j++) {
            int gn = bn + tc * 4 + j;
            float v = acc[i][j] + (bias ? bias[gn] : 0.f);
            if (ACT == 1) v = leaky_f(v);
            C[(size_t)gm * N + gn] = v;
        }
    }
}

// ---------------- S_partial = z[chunk].T @ M[chunk]  (z:[10000,64], M:[10000,512]) ----------------
// grid: (25 k-chunks of 400 rows, 4 n-tiles of 128). part: [25][64][512]
__global__ __launch_bounds__(256)
void ztm_partial(const float* __restrict__ Z, const float* __restrict__ Mm,
                 float* __restrict__ part) {
    const int kc = blockIdx.x;
    const int n0 = blockIdx.y * 128;
    const int tid = threadIdx.x;
    const int tr = tid >> 4;   // 0..15 -> 4 z-cols each
    const int tc = tid & 15;   // 0..15 -> 8 n-cols each
    __shared__ float sz[16][64 + 4];
    __shared__ float sm[16][128 + 4];
    float acc[4][8];
#pragma unroll
    for (int i = 0; i < 4; i++)
#pragma unroll
        for (int j = 0; j < 8; j++) acc[i][j] = 0.f;

    int kbase = kc * 400;
    for (int kt = 0; kt < 400; kt += 16) {
#pragma unroll
        for (int it = 0; it < 4; ++it) {
            int kk = (tid >> 6) + (it << 2);
            int c = tid & 63;
            sz[kk][c] = Z[(size_t)(kbase + kt + kk) * 64 + c];
        }
#pragma unroll
        for (int it = 0; it < 8; ++it) {
            int kk = (tid >> 7) + (it << 1);
            int n = tid & 127;
            sm[kk][n] = Mm[(size_t)(kbase + kt + kk) * 512 + n0 + n];
        }
        __syncthreads();
#pragma unroll
        for (int kk = 0; kk < 16; ++kk) {
            float a[4], b[8];
#pragma unroll
            for (int i = 0; i < 4; i++) a[i] = sz[kk][tr * 4 + i];
#pragma unroll
            for (int j = 0; j < 8; j++) b[j] = sm[kk][tc * 8 + j];
#pragma unroll
            for (int i = 0; i < 4; i++)
#pragma unroll
                for (int j = 0; j < 8; j++) acc[i][j] += a[i] * b[j];
        }
        __syncthreads();
    }
#pragma unroll
    for (int i = 0; i < 4; i++)
#pragma unroll
        for (int j = 0; j < 8; j++)
            part[(size_t)kc * (64 * 512) + (size_t)(tr * 4 + i) * 512 + n0 + tc * 8 + j] = acc[i][j];
}

__global__ void reduce_S(const float* __restrict__ part, float* __restrict__ S) {
    int i = blockIdx.x * blockDim.x + threadIdx.x;
    if (i < 64 * 512) {
        float s = 0.f;
#pragma unroll
        for (int c = 0; c < 25; ++c) s += part[(size_t)c * (64 * 512) + i];
        S[i] = s;
    }
}

// ---------------- launch ----------------
extern "C" void kernel_launch(void* const* d_in, const int* in_sizes, int n_in,
                              void* d_out, int out_size, void* d_ws, size_t ws_size,
                              hipStream_t stream) {
    const float* x    = (const float*)d_in[0];
    const int*   rows = (const int*)d_in[1];
    const int*   cols = (const int*)d_in[2];
    const float* vals = (const float*)d_in[3];
    const float* W1   = (const float*)d_in[4];
    const float* b1   = (const float*)d_in[5];
    const float* Wc1a = (const float*)d_in[6];
    const float* bc1a = (const float*)d_in[7];
    const float* Wc1b = (const float*)d_in[8];
    const float* bc1b = (const float*)d_in[9];
    const float* Wc2a = (const float*)d_in[10];
    const float* bc2a = (const float*)d_in[11];
    const float* Wc2b = (const float*)d_in[12];
    const float* bc2b = (const float*)d_in[13];
    const float* W6   = (const float*)d_in[14];
    const float* b6   = (const float*)d_in[15];

    const int N = in_sizes[0] / D_IN;      // 10000
    const int E = in_sizes[1];             // 320000

    float* ws = (float*)d_ws;
    float* C1   = ws;                    // [N,256]
    float* H    = ws + 2560000;          // [N,256]
    float* T1   = ws + 5120000;          // [N,128]
    float* T2   = ws + 6400000;          // [N,128]
    float* H2   = ws + 7680000;          // [N,256]
    float* MB   = ws + 10240000;         // [N,512]
    float* PART = ws + 15360000;         // [25,64,512]
    float* S    = ws + 16179200;         // [64,512]
    int* counts = (int*)(ws + 16211968); // [N]
    int* starts = counts + 10000;        // [N+1]
    int* cursor = starts + 10001;        // [N]
    int* eidx   = cursor + 10000;        // [E]

    float* Zp  = (float*)d_out + 5120000;   // z output region [N,64]
    float* Out = (float*)d_out;             // [N,512]

    const int GX = (N + 127) / 128;  // 79

    // 1. C1 = x @ W1
    gemm_f32<0><<<dim3(GX, 4), 256, 0, stream>>>(x, W1, nullptr, C1, N, D_H1, D_IN);

    // 2. CSR build
    zero_i32<<<(N + 255) / 256, 256, 0, stream>>>(counts, N);
    hist_kernel<<<(E + 255) / 256, 256, 0, stream>>>(rows, counts, E);
    scan_kernel<<<1, 1024, 0, stream>>>(counts, starts, cursor, N);
    scatter_kernel<<<(E + 255) / 256, 256, 0, stream>>>(rows, cursor, eidx, E);

    // 3. h = leaky(spmm + b1)
    spmm_leaky_kernel<<<N, 64, 0, stream>>>(starts, eidx, cols, vals, C1, b1, H);

    // 4. T1 = leaky(h @ Wc1a + bc1a)
    gemm_f32<1><<<dim3(GX, 2), 256, 0, stream>>>(H, Wc1a, bc1a, T1, N, D_C1A, D_H1);

    // 5. z = T1 @ Wc1b + bc1b   (second output)
    gemm_f32<0><<<dim3(GX, 1), 256, 0, stream>>>(T1, Wc1b, bc1b, Zp, N, D_Z, D_C1A);

    // 6. T2 = leaky(z @ Wc2a + bc2a)
    gemm_f32<1><<<dim3(GX, 2), 256, 0, stream>>>(Zp, Wc2a, bc2a, T2, N, D_C2A, D_Z);

    // 7. h2 = leaky(T2 @ Wc2b + bc2b)
    gemm_f32<1><<<dim3(GX, 4), 256, 0, stream>>>(T2, Wc2b, bc2b, H2, N, D_C2B, D_C2A);

    // 8. MB = h2 @ W6
    gemm_f32<0><<<dim3(GX, 8), 256, 0, stream>>>(H2, W6, nullptr, MB, N, D_OUT, D_C2B);

    // 9. S = z.T @ MB  (split-K partials, deterministic reduce)
    ztm_partial<<<dim3(25, 4), 256, 0, stream>>>(Zp, MB, PART);
    reduce_S<<<(64 * 512 + 255) / 256, 256, 0, stream>>>(PART, S);

    // 10. out = z @ S + b6
    gemm_f32<0><<<dim3(GX, 8), 256, 0, stream>>>(Zp, S, b6, Out, N, D_OUT, D_Z);
}

// Round 3
// 267.030 us; speedup vs baseline: 1.9248x; 1.9248x over previous
//
#include <hip/hip_runtime.h>
#include <hip/hip_bf16.h>

#define NROWS 10000

typedef __attribute__((ext_vector_type(8))) short bf16x8;
typedef __attribute__((ext_vector_type(4))) float f32x4;

__device__ __forceinline__ float leaky_f(float x) { return x >= 0.f ? x : 0.01f * x; }

__device__ __forceinline__ unsigned short f2bf(float f) {
    union { float f; unsigned int u; } v; v.f = f;
    unsigned int r = v.u + 0x7fffu + ((v.u >> 16) & 1u);
    return (unsigned short)(r >> 16);
}
__device__ __forceinline__ float bf2f(unsigned short h) {
    union { unsigned int u; float f; } v; v.u = ((unsigned int)h) << 16;
    return v.f;
}

// ---------------- conversions ----------------
__global__ void convsplit(const float* __restrict__ in, unsigned short* __restrict__ hi,
                          unsigned short* __restrict__ lo, int n4) {
    int i = blockIdx.x * blockDim.x + threadIdx.x;
    if (i < n4) {
        float4 v = ((const float4*)in)[i];
        ushort4 h, l;
        h.x = f2bf(v.x); l.x = f2bf(v.x - bf2f(h.x));
        h.y = f2bf(v.y); l.y = f2bf(v.y - bf2f(h.y));
        h.z = f2bf(v.z); l.z = f2bf(v.z - bf2f(h.z));
        h.w = f2bf(v.w); l.w = f2bf(v.w - bf2f(h.w));
        ((ushort4*)hi)[i] = h;
        ((ushort4*)lo)[i] = l;
    }
}

// W[K][N] f32 -> Wt hi/lo [N][K] bf16
__global__ void wconvt(const float* __restrict__ W, unsigned short* __restrict__ thi,
                       unsigned short* __restrict__ tlo, int K, int N) {
    int i = blockIdx.x * blockDim.x + threadIdx.x;
    if (i < K * N) {
        int k = i / N, n = i % N;
        float f = W[i];
        unsigned short h = f2bf(f);
        thi[(size_t)n * K + k] = h;
        tlo[(size_t)n * K + k] = f2bf(f - bf2f(h));
    }
}

// ---------------- CSR build ----------------
__global__ void zero_i32(int* __restrict__ p, int n) {
    int i = blockIdx.x * blockDim.x + threadIdx.x;
    if (i < n) p[i] = 0;
}

__global__ void hist_kernel(const int* __restrict__ rows, int* __restrict__ counts, int E) {
    int i = blockIdx.x * blockDim.x + threadIdx.x;
    if (i < E) atomicAdd(&counts[rows[i]], 1);
}

__global__ __launch_bounds__(1024)
void scan_kernel(const int* __restrict__ counts, int* __restrict__ starts,
                 int* __restrict__ cursor, int n) {
    __shared__ int buf[1024];
    __shared__ int base_s;
    int tid = threadIdx.x;
    if (tid == 0) base_s = 0;
    __syncthreads();
    for (int c0 = 0; c0 < n; c0 += 1024) {
        int i = c0 + tid;
        int v = (i < n) ? counts[i] : 0;
        buf[tid] = v;
        __syncthreads();
        for (int off = 1; off < 1024; off <<= 1) {
            int t = (tid >= off) ? buf[tid - off] : 0;
            __syncthreads();
            buf[tid] += t;
            __syncthreads();
        }
        int incl = buf[tid];
        int base = base_s;
        __syncthreads();
        if (i < n) { int ex = base + incl - v; starts[i] = ex; cursor[i] = ex; }
        if (tid == 1023) base_s = base + buf[1023];
        __syncthreads();
    }
    if (tid == 0) starts[n] = base_s;
}

__global__ void scatter_kernel(const int* __restrict__ rows, int* __restrict__ cursor,
                               int* __restrict__ eidx, int E) {
    int i = blockIdx.x * blockDim.x + threadIdx.x;
    if (i < E) {
        int pos = atomicAdd(&cursor[rows[i]], 1);
        eidx[pos] = i;
    }
}

// ---------------- SpMM: H = leaky(A_sp @ C1 + b1) -> hi/lo bf16 [N][256] ----------------
__global__ __launch_bounds__(64)
void spmm_leaky_kernel(const int* __restrict__ starts, const int* __restrict__ eidx,
                       const int* __restrict__ cols, const float* __restrict__ vals,
                       const float* __restrict__ C1, const float* __restrict__ b1,
                       unsigned short* __restrict__ Hhi, unsigned short* __restrict__ Hlo) {
    int r = blockIdx.x;
    int t = threadIdx.x;               // 0..63 -> 4 cols each
    const float4* C1v = (const float4*)C1;
    float4 a0 = ((const float4*)b1)[t];
    float4 a1 = {0.f, 0.f, 0.f, 0.f};
    int s = starts[r], e = starts[r + 1];
    int p = s;
    for (; p + 2 <= e; p += 2) {
        int e0 = eidx[p], e1 = eidx[p + 1];
        int c0 = cols[e0], c1 = cols[e1];
        float v0 = vals[e0], v1 = vals[e1];
        float4 s0 = C1v[(size_t)c0 * 64 + t];
        float4 s1 = C1v[(size_t)c1 * 64 + t];
        a0.x += v0 * s0.x; a0.y += v0 * s0.y; a0.z += v0 * s0.z; a0.w += v0 * s0.w;
        a1.x += v1 * s1.x; a1.y += v1 * s1.y; a1.z += v1 * s1.z; a1.w += v1 * s1.w;
    }
    if (p < e) {
        int e0 = eidx[p];
        int c0 = cols[e0];
        float v0 = vals[e0];
        float4 s0 = C1v[(size_t)c0 * 64 + t];
        a0.x += v0 * s0.x; a0.y += v0 * s0.y; a0.z += v0 * s0.z; a0.w += v0 * s0.w;
    }
    float f0 = leaky_f(a0.x + a1.x);
    float f1 = leaky_f(a0.y + a1.y);
    float f2 = leaky_f(a0.z + a1.z);
    float f3 = leaky_f(a0.w + a1.w);
    ushort4 h, l;
    h.x = f2bf(f0); l.x = f2bf(f0 - bf2f(h.x));
    h.y = f2bf(f1); l.y = f2bf(f1 - bf2f(h.y));
    h.z = f2bf(f2); l.z = f2bf(f2 - bf2f(h.z));
    h.w = f2bf(f3); l.w = f2bf(f3 - bf2f(h.w));
    ((ushort4*)Hhi)[(size_t)r * 64 + t] = h;
    ((ushort4*)Hlo)[(size_t)r * 64 + t] = l;
}

// ---------------- MFMA split-bf16 GEMM ----------------
// A[M][K] hi/lo bf16, Bt[N][K] hi/lo bf16 (B transposed), C = act(A@B + bias)
// BM=BN=64, BK=32, 256 threads (4 waves, each 32x32).
template<int ACT, int WF32, int WHILO>
__global__ __launch_bounds__(256)
void gemm_mfma(const unsigned short* __restrict__ Ahi, const unsigned short* __restrict__ Alo,
               const unsigned short* __restrict__ Bthi, const unsigned short* __restrict__ Btlo,
               const float* __restrict__ bias, float* __restrict__ Cf,
               unsigned short* __restrict__ Chi, unsigned short* __restrict__ Clo,
               int M, int N, int K) {
    __shared__ short sAh[64][40];
    __shared__ short sAl[64][40];
    __shared__ short sBh[64][40];
    __shared__ short sBl[64][40];
    const int bm = blockIdx.x * 64;
    const int bn = blockIdx.y * 64;
    const int tid = threadIdx.x;
    const int lane = tid & 63, wid = tid >> 6;
    const int wm = wid & 1, wn = wid >> 1;
    const int l15 = lane & 15, kg = lane >> 4;
    const int sm = tid >> 2;   // 0..63 staging row
    const int ks = tid & 3;    // 0..3  staging k-slot (8 bf16)

    f32x4 acc[2][2];
#pragma unroll
    for (int i = 0; i < 2; i++)
#pragma unroll
        for (int j = 0; j < 2; j++) acc[i][j] = (f32x4){0.f, 0.f, 0.f, 0.f};

    for (int k0 = 0; k0 < K; k0 += 32) {
        int gm = bm + sm;
        uint4 vh = {0u, 0u, 0u, 0u}, vl = {0u, 0u, 0u, 0u};
        if (gm < M) {
            vh = *(const uint4*)(Ahi + (size_t)gm * K + k0 + ks * 8);
            vl = *(const uint4*)(Alo + (size_t)gm * K + k0 + ks * 8);
        }
        *(uint4*)(&sAh[sm][ks * 8]) = vh;
        *(uint4*)(&sAl[sm][ks * 8]) = vl;
        uint4 wh = *(const uint4*)(Bthi + (size_t)(bn + sm) * K + k0 + ks * 8);
        uint4 wl = *(const uint4*)(Btlo + (size_t)(bn + sm) * K + k0 + ks * 8);
        *(uint4*)(&sBh[sm][ks * 8]) = wh;
        *(uint4*)(&sBl[sm][ks * 8]) = wl;
        __syncthreads();

        bf16x8 ah[2], al[2], bh[2], bl[2];
#pragma unroll
        for (int i = 0; i < 2; i++) {
            ah[i] = *(const bf16x8*)(&sAh[wm * 32 + i * 16 + l15][kg * 8]);
            al[i] = *(const bf16x8*)(&sAl[wm * 32 + i * 16 + l15][kg * 8]);
            bh[i] = *(const bf16x8*)(&sBh[wn * 32 + i * 16 + l15][kg * 8]);
            bl[i] = *(const bf16x8*)(&sBl[wn * 32 + i * 16 + l15][kg * 8]);
        }
#pragma unroll
        for (int i = 0; i < 2; i++)
#pragma unroll
            for (int j = 0; j < 2; j++) {
                acc[i][j] = __builtin_amdgcn_mfma_f32_16x16x32_bf16(ah[i], bh[j], acc[i][j], 0, 0, 0);
                acc[i][j] = __builtin_amdgcn_mfma_f32_16x16x32_bf16(al[i], bh[j], acc[i][j], 0, 0, 0);
                acc[i][j] = __builtin_amdgcn_mfma_f32_16x16x32_bf16(ah[i], bl[j], acc[i][j], 0, 0, 0);
            }
        __syncthreads();
    }

#pragma unroll
    for (int i = 0; i < 2; i++) {
        int row0 = wm * 32 + i * 16 + kg * 4;
#pragma unroll
        for (int j = 0; j < 2; j++) {
            int col = bn + wn * 32 + j * 16 + l15;
            float bv = bias ? bias[col] : 0.f;
#pragma unroll
            for (int r = 0; r < 4; r++) {
                int grow = bm + row0 + r;
                if (grow < M) {
                    float v = acc[i][j][r] + bv;
                    if (ACT) v = leaky_f(v);
                    if (WF32) Cf[(size_t)grow * N + col] = v;
                    if (WHILO) {
                        unsigned short h = f2bf(v);
                        Chi[(size_t)grow * N + col] = h;
                        Clo[(size_t)grow * N + col] = f2bf(v - bf2f(h));
                    }
                }
            }
        }
    }
}

// ---------------- S partials: z.T @ MB, f32, 50 chunks of 200 rows ----------------
__global__ __launch_bounds__(256)
void ztm_partial(const float* __restrict__ Z, const float* __restrict__ Mm,
                 float* __restrict__ part) {
    const int kc = blockIdx.x;            // 0..49
    const int n0 = blockIdx.y * 128;      // 0..3
    const int tid = threadIdx.x;
    const int tr = tid >> 4;   // 0..15 -> 4 z-cols each
    const int tc = tid & 15;   // 0..15 -> 8 n-cols each
    __shared__ float sz[8][68];
    __shared__ float sm8[8][132];
    float acc[4][8];
#pragma unroll
    for (int i = 0; i < 4; i++)
#pragma unroll
        for (int j = 0; j < 8; j++) acc[i][j] = 0.f;

    int kbase = kc * 200;
    for (int kt = 0; kt < 200; kt += 8) {
#pragma unroll
        for (int it = 0; it < 2; ++it) {
            int id = tid + it * 256;
            int kk = id >> 6, c = id & 63;
            sz[kk][c] = Z[(size_t)(kbase + kt + kk) * 64 + c];
        }
#pragma unroll
        for (int it = 0; it < 4; ++it) {
            int id = tid + it * 256;
            int kk = id >> 7, n = id & 127;
            sm8[kk][n] = Mm[(size_t)(kbase + kt + kk) * 512 + n0 + n];
        }
        __syncthreads();
#pragma unroll
        for (int kk = 0; kk < 8; ++kk) {
            float a[4], b[8];
#pragma unroll
            for (int i = 0; i < 4; i++) a[i] = sz[kk][tr * 4 + i];
#pragma unroll
            for (int j = 0; j < 8; j++) b[j] = sm8[kk][tc * 8 + j];
#pragma unroll
            for (int i = 0; i < 4; i++)
#pragma unroll
                for (int j = 0; j < 8; j++) acc[i][j] += a[i] * b[j];
        }
        __syncthreads();
    }
#pragma unroll
    for (int i = 0; i < 4; i++)
#pragma unroll
        for (int j = 0; j < 8; j++)
            part[(size_t)kc * (64 * 512) + (size_t)(tr * 4 + i) * 512 + n0 + tc * 8 + j] = acc[i][j];
}

// reduce 50 partials -> St hi/lo [512][64] (transposed, bf16)
__global__ void reduce_S(const float* __restrict__ part, unsigned short* __restrict__ Sthi,
                         unsigned short* __restrict__ Stlo) {
    int i = blockIdx.x * blockDim.x + threadIdx.x;
    if (i < 64 * 512) {
        float s = 0.f;
#pragma unroll
        for (int c = 0; c < 50; ++c) s += part[(size_t)c * (64 * 512) + i];
        int k = i >> 9, n = i & 511;
        unsigned short h = f2bf(s);
        Sthi[(size_t)n * 64 + k] = h;
        Stlo[(size_t)n * 64 + k] = f2bf(s - bf2f(h));
    }
}

// ---------------- launch ----------------
extern "C" void kernel_launch(void* const* d_in, const int* in_sizes, int n_in,
                              void* d_out, int out_size, void* d_ws, size_t ws_size,
                              hipStream_t stream) {
    const float* x    = (const float*)d_in[0];
    const int*   rows = (const int*)d_in[1];
    const int*   cols = (const int*)d_in[2];
    const float* vals = (const float*)d_in[3];
    const float* W1   = (const float*)d_in[4];
    const float* b1   = (const float*)d_in[5];
    const float* Wc1a = (const float*)d_in[6];
    const float* bc1a = (const float*)d_in[7];
    const float* Wc1b = (const float*)d_in[8];
    const float* bc1b = (const float*)d_in[9];
    const float* Wc2a = (const float*)d_in[10];
    const float* bc2a = (const float*)d_in[11];
    const float* Wc2b = (const float*)d_in[12];
    const float* bc2b = (const float*)d_in[13];
    const float* W6   = (const float*)d_in[14];
    const float* b6   = (const float*)d_in[15];

    const int N = NROWS;
    const int E = in_sizes[1];             // 320000

    float* ws = (float*)d_ws;
    // ---- workspace layout, float offsets; hi/lo pair of [R][C] needs R*C/2 floats EACH ----
    // [0 .. 5,120,000)           XHI/XLO  (2,560,000 each)   | MBp f32 [N][512] after gemm1
    // [5,120,000 .. 7,680,000)   C1 f32 [N][256]             | PART [50][64][512] after spmm
    // [7,680,000 .. 10,240,000)  HHI/HLO (1,280,000 each)    | H2HI/H2LO after gemm4
    // [10,240,000 .. 11,520,000) T1HI/T1LO (640,000 each)    | T2HI/T2LO after gemm5
    // [11,520,000 .. 12,160,000) ZHI/ZLO (320,000 each)
    // [12,160,000 ..)            ST + weights + CSR ints
    unsigned short* XHI  = (unsigned short*)(ws + 0);
    unsigned short* XLO  = (unsigned short*)(ws + 2560000);
    float*          MBp  = ws + 0;
    float*          C1   = ws + 5120000;
    float*          PART = ws + 5120000;
    unsigned short* HHI  = (unsigned short*)(ws + 7680000);
    unsigned short* HLO  = (unsigned short*)(ws + 8960000);
    unsigned short* T1HI = (unsigned short*)(ws + 10240000);
    unsigned short* T1LO = (unsigned short*)(ws + 10880000);
    unsigned short* ZHI  = (unsigned short*)(ws + 11520000);
    unsigned short* ZLO  = (unsigned short*)(ws + 11840000);
    unsigned short* T2HI = T1HI;   // alias: T1 dead after gemm5
    unsigned short* T2LO = T1LO;
    unsigned short* H2HI = HHI;    // alias: H dead after gemm4
    unsigned short* H2LO = HLO;
    unsigned short* STHI = (unsigned short*)(ws + 12160000);   // 16,384 floats
    unsigned short* STLO = (unsigned short*)(ws + 12176384);

    unsigned short* W1THI   = (unsigned short*)(ws + 12192768); // 65,536
    unsigned short* W1TLO   = (unsigned short*)(ws + 12258304);
    unsigned short* WC1ATHI = (unsigned short*)(ws + 12323840); // 16,384
    unsigned short* WC1ATLO = (unsigned short*)(ws + 12340224);
    unsigned short* WC1BTHI = (unsigned short*)(ws + 12356608); // 4,096
    unsigned short* WC1BTLO = (unsigned short*)(ws + 12360704);
    unsigned short* WC2ATHI = (unsigned short*)(ws + 12364800); // 4,096
    unsigned short* WC2ATLO = (unsigned short*)(ws + 12368896);
    unsigned short* WC2BTHI = (unsigned short*)(ws + 12372992); // 16,384
    unsigned short* WC2BTLO = (unsigned short*)(ws + 12389376);
    unsigned short* W6THI   = (unsigned short*)(ws + 12405760); // 65,536
    unsigned short* W6TLO   = (unsigned short*)(ws + 12471296);

    int* counts = (int*)(ws + 12536832); // [N]
    int* starts = counts + 10000;        // [N+1]
    int* cursor = starts + 10001;        // [N]
    int* eidx   = cursor + 10000;        // [E]   (ends ~12.89M floats = 51.5 MB)

    float* Out = (float*)d_out;             // [N,512]
    float* Zp  = (float*)d_out + 5120000;   // [N,64]

    const int GX = (N + 63) / 64;  // 157

    // conversions
    convsplit<<<5000, 256, 0, stream>>>(x, XHI, XLO, 1280000);
    wconvt<<<512, 256, 0, stream>>>(W1,   W1THI,   W1TLO,   512, 256);
    wconvt<<<128, 256, 0, stream>>>(Wc1a, WC1ATHI, WC1ATLO, 256, 128);
    wconvt<<< 32, 256, 0, stream>>>(Wc1b, WC1BTHI, WC1BTLO, 128,  64);
    wconvt<<< 32, 256, 0, stream>>>(Wc2a, WC2ATHI, WC2ATLO,  64, 128);
    wconvt<<<128, 256, 0, stream>>>(Wc2b, WC2BTHI, WC2BTLO, 128, 256);
    wconvt<<<512, 256, 0, stream>>>(W6,   W6THI,   W6TLO,   256, 512);

    // CSR build
    zero_i32<<<(N + 255) / 256, 256, 0, stream>>>(counts, N);
    hist_kernel<<<(E + 255) / 256, 256, 0, stream>>>(rows, counts, E);
    scan_kernel<<<1, 1024, 0, stream>>>(counts, starts, cursor, N);
    scatter_kernel<<<(E + 255) / 256, 256, 0, stream>>>(rows, cursor, eidx, E);

    // 1. C1 = x @ W1 (f32 out, for spmm gather)
    gemm_mfma<0,1,0><<<dim3(GX, 4), 256, 0, stream>>>(XHI, XLO, W1THI, W1TLO, nullptr,
                                                      C1, nullptr, nullptr, N, 256, 512);
    // 3. H = leaky(spmm + b1) -> hi/lo
    spmm_leaky_kernel<<<N, 64, 0, stream>>>(starts, eidx, cols, vals, C1, b1, HHI, HLO);

    // 4. T1 = leaky(H @ Wc1a + bc1a) -> hi/lo
    gemm_mfma<1,0,1><<<dim3(GX, 2), 256, 0, stream>>>(HHI, HLO, WC1ATHI, WC1ATLO, bc1a,
                                                      nullptr, T1HI, T1LO, N, 128, 256);
    // 5. z = T1 @ Wc1b + bc1b -> f32 output + hi/lo
    gemm_mfma<0,1,1><<<dim3(GX, 1), 256, 0, stream>>>(T1HI, T1LO, WC1BTHI, WC1BTLO, bc1b,
                                                      Zp, ZHI, ZLO, N, 64, 128);
    // 6. T2 = leaky(z @ Wc2a + bc2a) -> hi/lo   (T2 aliases T1 storage)
    gemm_mfma<1,0,1><<<dim3(GX, 2), 256, 0, stream>>>(ZHI, ZLO, WC2ATHI, WC2ATLO, bc2a,
                                                      nullptr, T2HI, T2LO, N, 128, 64);
    // 7. H2 = leaky(T2 @ Wc2b + bc2b) -> hi/lo  (H2 aliases H storage)
    gemm_mfma<1,0,1><<<dim3(GX, 4), 256, 0, stream>>>(T2HI, T2LO, WC2BTHI, WC2BTLO, bc2b,
                                                      nullptr, H2HI, H2LO, N, 256, 128);
    // 8. MB = H2 @ W6 -> f32 (MB aliases X storage)
    gemm_mfma<0,1,0><<<dim3(GX, 8), 256, 0, stream>>>(H2HI, H2LO, W6THI, W6TLO, nullptr,
                                                      MBp, nullptr, nullptr, N, 512, 256);
    // 9. S = z.T @ MB (split-K f32), reduce -> St hi/lo [512][64]  (PART aliases C1)
    ztm_partial<<<dim3(50, 4), 256, 0, stream>>>(Zp, MBp, PART);
    reduce_S<<<(64 * 512 + 255) / 256, 256, 0, stream>>>(PART, STHI, STLO);

    // 10. out = z @ S + b6
    gemm_mfma<0,1,0><<<dim3(GX, 8), 256, 0, stream>>>(ZHI, ZLO, STHI, STLO, b6,
                                                      Out, nullptr, nullptr, N, 512, 64);
}

// Round 4
// 194.116 us; speedup vs baseline: 2.6478x; 1.3756x over previous
//
#include <hip/hip_runtime.h>
#include <hip/hip_bf16.h>

#define NROWS 10000

typedef __attribute__((ext_vector_type(8))) short bf16x8;
typedef __attribute__((ext_vector_type(4))) float f32x4;

__device__ __forceinline__ float leaky_f(float x) { return x >= 0.f ? x : 0.01f * x; }

__device__ __forceinline__ unsigned short f2bf(float f) {
    union { float f; unsigned int u; } v; v.f = f;
    unsigned int r = v.u + 0x7fffu + ((v.u >> 16) & 1u);
    return (unsigned short)(r >> 16);
}
__device__ __forceinline__ float bf2f(unsigned short h) {
    union { unsigned int u; float f; } v; v.u = ((unsigned int)h) << 16;
    return v.f;
}

// ---------------- conversions ----------------
__global__ void convx(const float* __restrict__ in, unsigned short* __restrict__ hi, int n4) {
    int i = blockIdx.x * blockDim.x + threadIdx.x;
    if (i < n4) {
        float4 v = ((const float4*)in)[i];
        ushort4 h;
        h.x = f2bf(v.x); h.y = f2bf(v.y); h.z = f2bf(v.z); h.w = f2bf(v.w);
        ((ushort4*)hi)[i] = h;
    }
}

// all 6 weights, transposed to [N][K] bf16, one kernel
__global__ void wconv_all(const float* __restrict__ W1, const float* __restrict__ Wc1a,
                          const float* __restrict__ Wc1b, const float* __restrict__ Wc2a,
                          const float* __restrict__ Wc2b, const float* __restrict__ W6,
                          unsigned short* __restrict__ o1, unsigned short* __restrict__ o2,
                          unsigned short* __restrict__ o3, unsigned short* __restrict__ o4,
                          unsigned short* __restrict__ o5, unsigned short* __restrict__ o6) {
    int gid = blockIdx.x * 256 + threadIdx.x;
    if (gid < 131072) {                       // W1 512x256
        int i = gid, k = i >> 8, n = i & 255;
        o1[n * 512 + k] = f2bf(W1[i]);
    } else if (gid < 163840) {                // Wc1a 256x128
        int i = gid - 131072, k = i >> 7, n = i & 127;
        o2[n * 256 + k] = f2bf(Wc1a[i]);
    } else if (gid < 172032) {                // Wc1b 128x64
        int i = gid - 163840, k = i >> 6, n = i & 63;
        o3[n * 128 + k] = f2bf(Wc1b[i]);
    } else if (gid < 180224) {                // Wc2a 64x128
        int i = gid - 172032, k = i >> 7, n = i & 127;
        o4[n * 64 + k] = f2bf(Wc2a[i]);
    } else if (gid < 212992) {                // Wc2b 128x256
        int i = gid - 180224, k = i >> 8, n = i & 255;
        o5[n * 128 + k] = f2bf(Wc2b[i]);
    } else if (gid < 344064) {                // W6 256x512
        int i = gid - 212992, k = i >> 9, n = i & 511;
        o6[n * 256 + k] = f2bf(W6[i]);
    }
}

// ---------------- CSR build ----------------
__global__ void zero_i32(int* __restrict__ p, int n) {
    int i = blockIdx.x * blockDim.x + threadIdx.x;
    if (i < n) p[i] = 0;
}

__global__ void hist_kernel(const int* __restrict__ rows, int* __restrict__ counts, int E) {
    int i = blockIdx.x * blockDim.x + threadIdx.x;
    if (i < E) atomicAdd(&counts[rows[i]], 1);
}

__global__ __launch_bounds__(1024)
void scan_kernel(const int* __restrict__ counts, int* __restrict__ starts,
                 int* __restrict__ cursor, int n) {
    __shared__ int buf[1024];
    __shared__ int base_s;
    int tid = threadIdx.x;
    if (tid == 0) base_s = 0;
    __syncthreads();
    for (int c0 = 0; c0 < n; c0 += 1024) {
        int i = c0 + tid;
        int v = (i < n) ? counts[i] : 0;
        buf[tid] = v;
        __syncthreads();
        for (int off = 1; off < 1024; off <<= 1) {
            int t = (tid >= off) ? buf[tid - off] : 0;
            __syncthreads();
            buf[tid] += t;
            __syncthreads();
        }
        int incl = buf[tid];
        int base = base_s;
        __syncthreads();
        if (i < n) { int ex = base + incl - v; starts[i] = ex; cursor[i] = ex; }
        if (tid == 1023) base_s = base + buf[1023];
        __syncthreads();
    }
    if (tid == 0) starts[n] = base_s;
}

// scatter edges into row-sorted (col,val) arrays
__global__ void scatter_kernel(const int* __restrict__ rows, const int* __restrict__ cols,
                               const float* __restrict__ vals, int* __restrict__ cursor,
                               int* __restrict__ cols_s, float* __restrict__ vals_s, int E) {
    int i = blockIdx.x * blockDim.x + threadIdx.x;
    if (i < E) {
        int pos = atomicAdd(&cursor[rows[i]], 1);
        cols_s[pos] = cols[i];
        vals_s[pos] = vals[i];
    }
}

// ---------------- SpMM: H = leaky(A_sp @ C1 + b1), bf16 gather ----------------
__global__ __launch_bounds__(64)
void spmm_leaky_kernel(const int* __restrict__ starts, const int* __restrict__ cols_s,
                       const float* __restrict__ vals_s, const unsigned short* __restrict__ C1b,
                       const float* __restrict__ b1, unsigned short* __restrict__ Hb) {
    int r = blockIdx.x;
    int t = threadIdx.x;               // 0..63 -> 4 cols each (256 total)
    float4 a0 = ((const float4*)b1)[t];
    float4 a1 = {0.f, 0.f, 0.f, 0.f};
    int s = starts[r], e = starts[r + 1];
    int p = s;
    for (; p + 2 <= e; p += 2) {
        int c0 = cols_s[p], c1 = cols_s[p + 1];
        float v0 = vals_s[p], v1 = vals_s[p + 1];
        ushort4 s0 = ((const ushort4*)(C1b + (size_t)c0 * 256))[t];
        ushort4 s1 = ((const ushort4*)(C1b + (size_t)c1 * 256))[t];
        a0.x += v0 * bf2f(s0.x); a0.y += v0 * bf2f(s0.y);
        a0.z += v0 * bf2f(s0.z); a0.w += v0 * bf2f(s0.w);
        a1.x += v1 * bf2f(s1.x); a1.y += v1 * bf2f(s1.y);
        a1.z += v1 * bf2f(s1.z); a1.w += v1 * bf2f(s1.w);
    }
    if (p < e) {
        int c0 = cols_s[p];
        float v0 = vals_s[p];
        ushort4 s0 = ((const ushort4*)(C1b + (size_t)c0 * 256))[t];
        a0.x += v0 * bf2f(s0.x); a0.y += v0 * bf2f(s0.y);
        a0.z += v0 * bf2f(s0.z); a0.w += v0 * bf2f(s0.w);
    }
    ushort4 h;
    h.x = f2bf(leaky_f(a0.x + a1.x));
    h.y = f2bf(leaky_f(a0.y + a1.y));
    h.z = f2bf(leaky_f(a0.z + a1.z));
    h.w = f2bf(leaky_f(a0.w + a1.w));
    ((ushort4*)Hb)[(size_t)r * 64 + t] = h;
}

// ---------------- MFMA bf16 GEMM ----------------
// A[M][K] bf16, Bt[N][K] bf16 (B transposed), C = act(A@B + bias)
// BM=BN=64, BK=64, 256 threads (4 waves, each 32x32 of C).
template<int ACT, int WF32, int WBF>
__global__ __launch_bounds__(256)
void gemm_mfma(const unsigned short* __restrict__ A, const unsigned short* __restrict__ Bt,
               const float* __restrict__ bias, float* __restrict__ Cf,
               unsigned short* __restrict__ Cb, int M, int N, int K) {
    __shared__ short sA[64][72];
    __shared__ short sB[64][72];
    const int bm = blockIdx.x * 64;
    const int bn = blockIdx.y * 64;
    const int tid = threadIdx.x;
    const int lane = tid & 63, wid = tid >> 6;
    const int wm = wid & 1, wn = wid >> 1;
    const int l15 = lane & 15, kg = lane >> 4;

    f32x4 acc[2][2];
#pragma unroll
    for (int i = 0; i < 2; i++)
#pragma unroll
        for (int j = 0; j < 2; j++) acc[i][j] = (f32x4){0.f, 0.f, 0.f, 0.f};

    for (int k0 = 0; k0 < K; k0 += 64) {
        // stage 64x64 bf16 tiles: 512 uint4 each, 2 per thread
#pragma unroll
        for (int it = 0; it < 2; ++it) {
            int idx = tid + it * 256;
            int r = idx >> 3, s = idx & 7;
            int gm = bm + r;
            uint4 va = {0u, 0u, 0u, 0u};
            if (gm < M) va = *(const uint4*)(A + (size_t)gm * K + k0 + s * 8);
            *(uint4*)(&sA[r][s * 8]) = va;
            uint4 vb = *(const uint4*)(Bt + (size_t)(bn + r) * K + k0 + s * 8);
            *(uint4*)(&sB[r][s * 8]) = vb;
        }
        __syncthreads();

        bf16x8 a[2][2], b[2][2];
#pragma unroll
        for (int i = 0; i < 2; i++)
#pragma unroll
            for (int ks = 0; ks < 2; ++ks) {
                a[i][ks] = *(const bf16x8*)(&sA[wm * 32 + i * 16 + l15][kg * 8 + ks * 32]);
                b[i][ks] = *(const bf16x8*)(&sB[wn * 32 + i * 16 + l15][kg * 8 + ks * 32]);
            }
#pragma unroll
        for (int ks = 0; ks < 2; ++ks)
#pragma unroll
            for (int i = 0; i < 2; i++)
#pragma unroll
                for (int j = 0; j < 2; j++)
                    acc[i][j] = __builtin_amdgcn_mfma_f32_16x16x32_bf16(a[i][ks], b[j][ks], acc[i][j], 0, 0, 0);
        __syncthreads();
    }

#pragma unroll
    for (int i = 0; i < 2; i++) {
        int row0 = wm * 32 + i * 16 + kg * 4;
#pragma unroll
        for (int j = 0; j < 2; j++) {
            int col = bn + wn * 32 + j * 16 + l15;
            float bv = bias ? bias[col] : 0.f;
#pragma unroll
            for (int r = 0; r < 4; r++) {
                int grow = bm + row0 + r;
                if (grow < M) {
                    float v = acc[i][j][r] + bv;
                    if (ACT) v = leaky_f(v);
                    if (WF32) Cf[(size_t)grow * N + col] = v;
                    if (WBF)  Cb[(size_t)grow * N + col] = f2bf(v);
                }
            }
        }
    }
}

// ---------------- S partials: z.T @ MB, f32, 50 chunks of 200 rows ----------------
__global__ __launch_bounds__(256)
void ztm_partial(const float* __restrict__ Z, const float* __restrict__ Mm,
                 float* __restrict__ part) {
    const int kc = blockIdx.x;            // 0..49
    const int n0 = blockIdx.y * 128;      // 0..3
    const int tid = threadIdx.x;
    const int tr = tid >> 4;   // 0..15 -> 4 z-cols each
    const int tc = tid & 15;   // 0..15 -> 8 n-cols each
    __shared__ float sz[8][68];
    __shared__ float sm8[8][132];
    float acc[4][8];
#pragma unroll
    for (int i = 0; i < 4; i++)
#pragma unroll
        for (int j = 0; j < 8; j++) acc[i][j] = 0.f;

    int kbase = kc * 200;
    for (int kt = 0; kt < 200; kt += 8) {
#pragma unroll
        for (int it = 0; it < 2; ++it) {
            int id = tid + it * 256;
            int kk = id >> 6, c = id & 63;
            sz[kk][c] = Z[(size_t)(kbase + kt + kk) * 64 + c];
        }
#pragma unroll
        for (int it = 0; it < 4; ++it) {
            int id = tid + it * 256;
            int kk = id >> 7, n = id & 127;
            sm8[kk][n] = Mm[(size_t)(kbase + kt + kk) * 512 + n0 + n];
        }
        __syncthreads();
#pragma unroll
        for (int kk = 0; kk < 8; ++kk) {
            float a[4], b[8];
#pragma unroll
            for (int i = 0; i < 4; i++) a[i] = sz[kk][tr * 4 + i];
#pragma unroll
            for (int j = 0; j < 8; j++) b[j] = sm8[kk][tc * 8 + j];
#pragma unroll
            for (int i = 0; i < 4; i++)
#pragma unroll
                for (int j = 0; j < 8; j++) acc[i][j] += a[i] * b[j];
        }
        __syncthreads();
    }
#pragma unroll
    for (int i = 0; i < 4; i++)
#pragma unroll
        for (int j = 0; j < 8; j++)
            part[(size_t)kc * (64 * 512) + (size_t)(tr * 4 + i) * 512 + n0 + tc * 8 + j] = acc[i][j];
}

// reduce 50 partials -> St bf16 [512][64] (transposed)
__global__ void reduce_S(const float* __restrict__ part, unsigned short* __restrict__ Stb) {
    int i = blockIdx.x * blockDim.x + threadIdx.x;
    if (i < 64 * 512) {
        float s = 0.f;
#pragma unroll
        for (int c = 0; c < 50; ++c) s += part[(size_t)c * (64 * 512) + i];
        int k = i >> 9, n = i & 511;
        Stb[(size_t)n * 64 + k] = f2bf(s);
    }
}

// ---------------- launch ----------------
extern "C" void kernel_launch(void* const* d_in, const int* in_sizes, int n_in,
                              void* d_out, int out_size, void* d_ws, size_t ws_size,
                              hipStream_t stream) {
    const float* x    = (const float*)d_in[0];
    const int*   rows = (const int*)d_in[1];
    const int*   cols = (const int*)d_in[2];
    const float* vals = (const float*)d_in[3];
    const float* W1   = (const float*)d_in[4];
    const float* b1   = (const float*)d_in[5];
    const float* Wc1a = (const float*)d_in[6];
    const float* bc1a = (const float*)d_in[7];
    const float* Wc1b = (const float*)d_in[8];
    const float* bc1b = (const float*)d_in[9];
    const float* Wc2a = (const float*)d_in[10];
    const float* bc2a = (const float*)d_in[11];
    const float* Wc2b = (const float*)d_in[12];
    const float* bc2b = (const float*)d_in[13];
    const float* W6   = (const float*)d_in[14];
    const float* b6   = (const float*)d_in[15];

    const int N = NROWS;
    const int E = in_sizes[1];             // 320000

    float* ws = (float*)d_ws;
    // ---- workspace (float offsets) ----
    // [0 .. 2,560,000)          XHI [10000][512] bf16          | dead after g1
    // [0 .. 5,120,000)          MBp f32 [10000][512]           (written by g8)
    // [2,560,000 .. 3,840,000)  C1b [10000][256] bf16          | dead after spmm
    // [5,120,000 .. 6,758,400)  PART [50][64][512] f32
    // [6,758,400 .. 8,038,400)  HHI [10000][256] bf16          | H2 aliases after g4
    // [8,038,400 .. 8,678,400)  T1HI [10000][128] bf16         | T2 aliases after g5
    // [8,678,400 .. 8,998,400)  ZHI [10000][64] bf16
    // [8,998,400 .. 9,014,784)  STB [512][64] bf16
    // [9,014,784 ..)            weights bf16, then CSR ints
    unsigned short* XHI  = (unsigned short*)(ws + 0);
    float*          MBp  = ws + 0;
    unsigned short* C1b  = (unsigned short*)(ws + 2560000);
    float*          PART = ws + 5120000;
    unsigned short* HHI  = (unsigned short*)(ws + 6758400);
    unsigned short* T1HI = (unsigned short*)(ws + 8038400);
    unsigned short* ZHI  = (unsigned short*)(ws + 8678400);
    unsigned short* T2HI = T1HI;
    unsigned short* H2HI = HHI;
    unsigned short* STB  = (unsigned short*)(ws + 8998400);

    unsigned short* W1T   = (unsigned short*)(ws + 9014784);  // 65,536 fl
    unsigned short* WC1AT = (unsigned short*)(ws + 9080320);  // 16,384
    unsigned short* WC1BT = (unsigned short*)(ws + 9096704);  //  4,096
    unsigned short* WC2AT = (unsigned short*)(ws + 9100800);  //  4,096
    unsigned short* WC2BT = (unsigned short*)(ws + 9104896);  // 16,384
    unsigned short* W6T   = (unsigned short*)(ws + 9121280);  // 65,536

    int*   counts = (int*)(ws + 9186816);   // [10000]
    int*   starts = counts + 10000;         // [10001]
    int*   cursor = starts + 10001;         // [10000]
    int*   cols_s = cursor + 10000;         // [E]
    float* vals_s = (float*)(cols_s + 320000); // [E]  ends ~9.87M floats = 39.5 MB

    float* Out = (float*)d_out;             // [N,512]
    float* Zp  = (float*)d_out + 5120000;   // [N,64]

    const int GX = (N + 63) / 64;  // 157

    // conversions
    convx<<<5000, 256, 0, stream>>>(x, XHI, 1280000);
    wconv_all<<<1344, 256, 0, stream>>>(W1, Wc1a, Wc1b, Wc2a, Wc2b, W6,
                                        W1T, WC1AT, WC1BT, WC2AT, WC2BT, W6T);

    // CSR build (row-sorted col/val arrays)
    zero_i32<<<(N + 255) / 256, 256, 0, stream>>>(counts, N);
    hist_kernel<<<(E + 255) / 256, 256, 0, stream>>>(rows, counts, E);
    scan_kernel<<<1, 1024, 0, stream>>>(counts, starts, cursor, N);
    scatter_kernel<<<(E + 255) / 256, 256, 0, stream>>>(rows, cols, vals, cursor, cols_s, vals_s, E);

    // 1. C1 = x @ W1 -> bf16 (for spmm gather)
    gemm_mfma<0,0,1><<<dim3(GX, 4), 256, 0, stream>>>(XHI, W1T, nullptr,
                                                      nullptr, C1b, N, 256, 512);
    // 3. H = leaky(spmm + b1) -> bf16
    spmm_leaky_kernel<<<N, 64, 0, stream>>>(starts, cols_s, vals_s, C1b, b1, HHI);

    // 4. T1 = leaky(H @ Wc1a + bc1a) -> bf16
    gemm_mfma<1,0,1><<<dim3(GX, 2), 256, 0, stream>>>(HHI, WC1AT, bc1a,
                                                      nullptr, T1HI, N, 128, 256);
    // 5. z = T1 @ Wc1b + bc1b -> f32 output + bf16
    gemm_mfma<0,1,1><<<dim3(GX, 1), 256, 0, stream>>>(T1HI, WC1BT, bc1b,
                                                      Zp, ZHI, N, 64, 128);
    // 6. T2 = leaky(z @ Wc2a + bc2a) -> bf16 (aliases T1)
    gemm_mfma<1,0,1><<<dim3(GX, 2), 256, 0, stream>>>(ZHI, WC2AT, bc2a,
                                                      nullptr, T2HI, N, 128, 64);
    // 7. H2 = leaky(T2 @ Wc2b + bc2b) -> bf16 (aliases H)
    gemm_mfma<1,0,1><<<dim3(GX, 4), 256, 0, stream>>>(T2HI, WC2BT, bc2b,
                                                      nullptr, H2HI, N, 256, 128);
    // 8. MB = H2 @ W6 -> f32 (aliases X/C1 region)
    gemm_mfma<0,1,0><<<dim3(GX, 8), 256, 0, stream>>>(H2HI, W6T, nullptr,
                                                      MBp, nullptr, N, 512, 256);
    // 9. S = z.T @ MB (split-K f32), reduce -> St bf16 [512][64]
    ztm_partial<<<dim3(50, 4), 256, 0, stream>>>(Zp, MBp, PART);
    reduce_S<<<(64 * 512 + 255) / 256, 256, 0, stream>>>(PART, STB);

    // 10. out = z @ S + b6 -> f32
    gemm_mfma<0,1,0><<<dim3(GX, 8), 256, 0, stream>>>(ZHI, STB, b6,
                                                      Out, nullptr, N, 512, 64);
}

// Round 6
// 158.870 us; speedup vs baseline: 3.2352x; 1.2219x over previous
//
#include <hip/hip_runtime.h>
#include <hip/hip_bf16.h>

#define NROWS 10000
#define KPAD  10240

typedef __attribute__((ext_vector_type(8))) short bf16x8;
typedef __attribute__((ext_vector_type(4))) float f32x4;

__device__ __forceinline__ float leaky_f(float x) { return x >= 0.f ? x : 0.01f * x; }

__device__ __forceinline__ unsigned short f2bf(float f) {
    union { float f; unsigned int u; } v; v.f = f;
    unsigned int r = v.u + 0x7fffu + ((v.u >> 16) & 1u);
    return (unsigned short)(r >> 16);
}
__device__ __forceinline__ float bf2f(unsigned short h) {
    union { unsigned int u; float f; } v; v.u = ((unsigned int)h) << 16;
    return v.f;
}

// ---------------- merged conversions + zero-init ----------------
__global__ void conv_all(const float* __restrict__ x, const float* __restrict__ W1,
                         const float* __restrict__ Wc1a, const float* __restrict__ Wc1b,
                         const float* __restrict__ Wc2a, const float* __restrict__ Wc2b,
                         const float* __restrict__ W6,
                         unsigned short* __restrict__ XHI,
                         unsigned short* __restrict__ o1, unsigned short* __restrict__ o2,
                         unsigned short* __restrict__ o3, unsigned short* __restrict__ o4,
                         unsigned short* __restrict__ o5, unsigned short* __restrict__ o6,
                         int* __restrict__ counts, unsigned short* __restrict__ Zt,
                         unsigned short* __restrict__ MBt) {
    int gid = blockIdx.x * 256 + threadIdx.x;
    if (gid < 1280000) {
        float4 v = ((const float4*)x)[gid];
        ushort4 h;
        h.x = f2bf(v.x); h.y = f2bf(v.y); h.z = f2bf(v.z); h.w = f2bf(v.w);
        ((ushort4*)XHI)[gid] = h;
    } else if (gid < 1411072) {           // W1 512x256
        int i = gid - 1280000, k = i >> 8, n = i & 255;
        o1[n * 512 + k] = f2bf(W1[i]);
    } else if (gid < 1443840) {           // Wc1a 256x128
        int i = gid - 1411072, k = i >> 7, n = i & 127;
        o2[n * 256 + k] = f2bf(Wc1a[i]);
    } else if (gid < 1452032) {           // Wc1b 128x64
        int i = gid - 1443840, k = i >> 6, n = i & 63;
        o3[n * 128 + k] = f2bf(Wc1b[i]);
    } else if (gid < 1460224) {           // Wc2a 64x128
        int i = gid - 1452032, k = i >> 7, n = i & 127;
        o4[n * 64 + k] = f2bf(Wc2a[i]);
    } else if (gid < 1492992) {           // Wc2b 128x256
        int i = gid - 1460224, k = i >> 8, n = i & 255;
        o5[n * 128 + k] = f2bf(Wc2b[i]);
    } else if (gid < 1624064) {           // W6 256x512
        int i = gid - 1492992, k = i >> 9, n = i & 511;
        o6[n * 256 + k] = f2bf(W6[i]);
    } else if (gid < 1634064) {
        counts[gid - 1624064] = 0;
    } else if (gid < 1649424) {           // ZT pad tail [64][10000..10240)
        int i = gid - 1634064;
        Zt[(size_t)(i / 240) * KPAD + 10000 + (i % 240)] = 0;
    } else if (gid < 1772304) {           // MBt pad tail [512][10000..10240)
        int i = gid - 1649424;
        MBt[(size_t)(i / 240) * KPAD + 10000 + (i % 240)] = 0;
    }
}

// ---------------- CSR build ----------------
__global__ void hist_kernel(const int* __restrict__ rows, int* __restrict__ counts, int E) {
    int i = blockIdx.x * blockDim.x + threadIdx.x;
    if (i < E) atomicAdd(&counts[rows[i]], 1);
}

__global__ __launch_bounds__(1024)
void scan_kernel(const int* __restrict__ counts, int* __restrict__ starts,
                 int* __restrict__ cursor, int n) {
    __shared__ int buf[1024];
    __shared__ int base_s;
    int tid = threadIdx.x;
    if (tid == 0) base_s = 0;
    __syncthreads();
    for (int c0 = 0; c0 < n; c0 += 1024) {
        int i = c0 + tid;
        int v = (i < n) ? counts[i] : 0;
        buf[tid] = v;
        __syncthreads();
        for (int off = 1; off < 1024; off <<= 1) {
            int t = (tid >= off) ? buf[tid - off] : 0;
            __syncthreads();
            buf[tid] += t;
            __syncthreads();
        }
        int incl = buf[tid];
        int base = base_s;
        __syncthreads();
        if (i < n) { int ex = base + incl - v; starts[i] = ex; cursor[i] = ex; }
        if (tid == 1023) base_s = base + buf[1023];
        __syncthreads();
    }
    if (tid == 0) starts[n] = base_s;
}

__global__ void scatter_kernel(const int* __restrict__ rows, const int* __restrict__ cols,
                               const float* __restrict__ vals, int* __restrict__ cursor,
                               int* __restrict__ cols_s, float* __restrict__ vals_s, int E) {
    int i = blockIdx.x * blockDim.x + threadIdx.x;
    if (i < E) {
        int pos = atomicAdd(&cursor[rows[i]], 1);
        cols_s[pos] = cols[i];
        vals_s[pos] = vals[i];
    }
}

// ---------------- SpMM: H = leaky(A_sp @ C1 + b1), bf16 gather ----------------
__global__ __launch_bounds__(64)
void spmm_leaky_kernel(const int* __restrict__ starts, const int* __restrict__ cols_s,
                       const float* __restrict__ vals_s, const unsigned short* __restrict__ C1b,
                       const float* __restrict__ b1, unsigned short* __restrict__ Hb) {
    int r = blockIdx.x;
    int t = threadIdx.x;
    float4 a0 = ((const float4*)b1)[t];
    float4 a1 = {0.f, 0.f, 0.f, 0.f};
    int s = starts[r], e = starts[r + 1];
    int p = s;
    for (; p + 2 <= e; p += 2) {
        int c0 = cols_s[p], c1 = cols_s[p + 1];
        float v0 = vals_s[p], v1 = vals_s[p + 1];
        ushort4 s0 = ((const ushort4*)(C1b + (size_t)c0 * 256))[t];
        ushort4 s1 = ((const ushort4*)(C1b + (size_t)c1 * 256))[t];
        a0.x += v0 * bf2f(s0.x); a0.y += v0 * bf2f(s0.y);
        a0.z += v0 * bf2f(s0.z); a0.w += v0 * bf2f(s0.w);
        a1.x += v1 * bf2f(s1.x); a1.y += v1 * bf2f(s1.y);
        a1.z += v1 * bf2f(s1.z); a1.w += v1 * bf2f(s1.w);
    }
    if (p < e) {
        int c0 = cols_s[p];
        float v0 = vals_s[p];
        ushort4 s0 = ((const ushort4*)(C1b + (size_t)c0 * 256))[t];
        a0.x += v0 * bf2f(s0.x); a0.y += v0 * bf2f(s0.y);
        a0.z += v0 * bf2f(s0.z); a0.w += v0 * bf2f(s0.w);
    }
    ushort4 h;
    h.x = f2bf(leaky_f(a0.x + a1.x));
    h.y = f2bf(leaky_f(a0.y + a1.y));
    h.z = f2bf(leaky_f(a0.z + a1.z));
    h.w = f2bf(leaky_f(a0.w + a1.w));
    ((ushort4*)Hb)[(size_t)r * 64 + t] = h;
}

// ---------------- generic MFMA bf16 GEMM ----------------
template<int ACT, int WF32, int WBF, int WTB>
__global__ __launch_bounds__(256)
void gemm_mfma(const unsigned short* __restrict__ A, const unsigned short* __restrict__ Bt,
               const float* __restrict__ bias, float* __restrict__ Cf,
               unsigned short* __restrict__ Cb, unsigned short* __restrict__ Ct,
               int ldt, int M, int N, int K) {
    __shared__ short sA[64][72];
    __shared__ short sB[64][72];
    const int bm = blockIdx.x * 64;
    const int bn = blockIdx.y * 64;
    const int tid = threadIdx.x;
    const int lane = tid & 63, wid = tid >> 6;
    const int wm = wid & 1, wn = wid >> 1;
    const int l15 = lane & 15, kg = lane >> 4;

    f32x4 acc[2][2];
#pragma unroll
    for (int i = 0; i < 2; i++)
#pragma unroll
        for (int j = 0; j < 2; j++) acc[i][j] = (f32x4){0.f, 0.f, 0.f, 0.f};

    for (int k0 = 0; k0 < K; k0 += 64) {
#pragma unroll
        for (int it = 0; it < 2; ++it) {
            int idx = tid + it * 256;
            int r = idx >> 3, s = idx & 7;
            int gm = bm + r;
            uint4 va = {0u, 0u, 0u, 0u};
            if (gm < M) va = *(const uint4*)(A + (size_t)gm * K + k0 + s * 8);
            *(uint4*)(&sA[r][s * 8]) = va;
            uint4 vb = *(const uint4*)(Bt + (size_t)(bn + r) * K + k0 + s * 8);
            *(uint4*)(&sB[r][s * 8]) = vb;
        }
        __syncthreads();
        bf16x8 a[2][2], b[2][2];
#pragma unroll
        for (int i = 0; i < 2; i++)
#pragma unroll
            for (int ks = 0; ks < 2; ++ks) {
                a[i][ks] = *(const bf16x8*)(&sA[wm * 32 + i * 16 + l15][kg * 8 + ks * 32]);
                b[i][ks] = *(const bf16x8*)(&sB[wn * 32 + i * 16 + l15][kg * 8 + ks * 32]);
            }
#pragma unroll
        for (int ks = 0; ks < 2; ++ks)
#pragma unroll
            for (int i = 0; i < 2; i++)
#pragma unroll
                for (int j = 0; j < 2; j++)
                    acc[i][j] = __builtin_amdgcn_mfma_f32_16x16x32_bf16(a[i][ks], b[j][ks], acc[i][j], 0, 0, 0);
        __syncthreads();
    }

#pragma unroll
    for (int i = 0; i < 2; i++) {
        int row0 = wm * 32 + i * 16 + kg * 4;
#pragma unroll
        for (int j = 0; j < 2; j++) {
            int col = bn + wn * 32 + j * 16 + l15;
            float bv = bias ? bias[col] : 0.f;
            ushort4 tw;
#pragma unroll
            for (int r = 0; r < 4; r++) {
                int grow = bm + row0 + r;
                float v = acc[i][j][r] + bv;
                if (ACT) v = leaky_f(v);
                if (WF32) { if (grow < M) Cf[(size_t)grow * N + col] = v; }
                if (WBF)  { if (grow < M) Cb[(size_t)grow * N + col] = f2bf(v); }
                if (WTB)  ((unsigned short*)&tw)[r] = f2bf(v);
            }
            if (WTB && (bm + row0) < M)
                *(ushort4*)(&Ct[(size_t)col * ldt + bm + row0]) = tw;
        }
    }
}

// ---------------- fused encoder tail: H -> T1 (LDS) -> z ----------------
__global__ __launch_bounds__(256)
void fused_enc(const unsigned short* __restrict__ H,   // [M][256]
               const unsigned short* __restrict__ Wa,  // [128][256]
               const unsigned short* __restrict__ Wb,  // [64][128]
               const float* __restrict__ ba, const float* __restrict__ bb,
               float* __restrict__ Zf, unsigned short* __restrict__ Zb,
               unsigned short* __restrict__ Zt, int M) {
    __shared__ short sA[64][72];
    __shared__ short sB[128][72];
    __shared__ short sT1[64][136];
    __shared__ short sWb[64][136];
    const int bm = blockIdx.x * 64;
    const int tid = threadIdx.x;
    const int lane = tid & 63, wid = tid >> 6;
    const int wm = wid & 1, wn = wid >> 1;
    const int l15 = lane & 15, kg = lane >> 4;

    // stage Wc1b whole (64x128 = 1024 uint4)  [FIX: was it<2 with r=idx>>4 covering rows 0..31 only]
#pragma unroll
    for (int it = 0; it < 4; ++it) {
        int idx = tid + it * 256;
        int r = idx >> 4, s = idx & 15;
        *(uint4*)(&sWb[r][s * 8]) = *(const uint4*)(Wb + r * 128 + s * 8);
    }

    // phase A: T1[64][128] = leaky(H @ Wc1a + ba)
    f32x4 accA[2][4];
#pragma unroll
    for (int i = 0; i < 2; i++)
#pragma unroll
        for (int j = 0; j < 4; j++) accA[i][j] = (f32x4){0.f, 0.f, 0.f, 0.f};

    for (int k0 = 0; k0 < 256; k0 += 64) {
#pragma unroll
        for (int it = 0; it < 2; ++it) {
            int idx = tid + it * 256;
            int r = idx >> 3, s = idx & 7;
            int gm = bm + r;
            uint4 va = {0u, 0u, 0u, 0u};
            if (gm < M) va = *(const uint4*)(H + (size_t)gm * 256 + k0 + s * 8);
            *(uint4*)(&sA[r][s * 8]) = va;
        }
#pragma unroll
        for (int it = 0; it < 4; ++it) {
            int idx = tid + it * 256;
            int r = idx >> 3, s = idx & 7;
            *(uint4*)(&sB[r][s * 8]) = *(const uint4*)(Wa + r * 256 + k0 + s * 8);
        }
        __syncthreads();
#pragma unroll
        for (int ks = 0; ks < 2; ++ks) {
            bf16x8 a[2], b[4];
#pragma unroll
            for (int i = 0; i < 2; i++)
                a[i] = *(const bf16x8*)(&sA[wm * 32 + i * 16 + l15][kg * 8 + ks * 32]);
#pragma unroll
            for (int j = 0; j < 4; j++)
                b[j] = *(const bf16x8*)(&sB[wn * 64 + j * 16 + l15][kg * 8 + ks * 32]);
#pragma unroll
            for (int i = 0; i < 2; i++)
#pragma unroll
                for (int j = 0; j < 4; j++)
                    accA[i][j] = __builtin_amdgcn_mfma_f32_16x16x32_bf16(a[i], b[j], accA[i][j], 0, 0, 0);
        }
        __syncthreads();
    }
#pragma unroll
    for (int i = 0; i < 2; i++) {
        int row0 = wm * 32 + i * 16 + kg * 4;
#pragma unroll
        for (int j = 0; j < 4; j++) {
            int col = wn * 64 + j * 16 + l15;
            float bv = ba[col];
#pragma unroll
            for (int r = 0; r < 4; r++)
                sT1[row0 + r][col] = f2bf(leaky_f(accA[i][j][r] + bv));
        }
    }
    __syncthreads();

    // phase B: z[64][64] = T1 @ Wc1b + bb
    f32x4 accB[2][2];
#pragma unroll
    for (int i = 0; i < 2; i++)
#pragma unroll
        for (int j = 0; j < 2; j++) accB[i][j] = (f32x4){0.f, 0.f, 0.f, 0.f};
#pragma unroll
    for (int kc = 0; kc < 4; ++kc) {
        bf16x8 a[2], b[2];
#pragma unroll
        for (int i = 0; i < 2; i++)
            a[i] = *(const bf16x8*)(&sT1[wm * 32 + i * 16 + l15][kc * 32 + kg * 8]);
#pragma unroll
        for (int j = 0; j < 2; j++)
            b[j] = *(const bf16x8*)(&sWb[wn * 32 + j * 16 + l15][kc * 32 + kg * 8]);
#pragma unroll
        for (int i = 0; i < 2; i++)
#pragma unroll
            for (int j = 0; j < 2; j++)
                accB[i][j] = __builtin_amdgcn_mfma_f32_16x16x32_bf16(a[i], b[j], accB[i][j], 0, 0, 0);
    }
#pragma unroll
    for (int i = 0; i < 2; i++) {
        int row0 = wm * 32 + i * 16 + kg * 4;
#pragma unroll
        for (int j = 0; j < 2; j++) {
            int col = wn * 32 + j * 16 + l15;
            float bv = bb[col];
            ushort4 tw;
#pragma unroll
            for (int r = 0; r < 4; r++) {
                int grow = bm + row0 + r;
                float v = accB[i][j][r] + bv;
                if (grow < M) {
                    Zf[(size_t)grow * 64 + col] = v;
                    Zb[(size_t)grow * 64 + col] = f2bf(v);
                }
                ((unsigned short*)&tw)[r] = f2bf(v);
            }
            if ((bm + row0) < M)
                *(ushort4*)(&Zt[(size_t)col * KPAD + bm + row0]) = tw;
        }
    }
}

// ---------------- fused decoder head: z -> T2 (LDS) -> H2 ----------------
__global__ __launch_bounds__(256)
void fused_dec(const unsigned short* __restrict__ Z,   // [M][64]
               const unsigned short* __restrict__ Wa,  // [128][64]
               const unsigned short* __restrict__ Wb,  // [256][128]
               const float* __restrict__ ba, const float* __restrict__ bb,
               unsigned short* __restrict__ H2, int M) {
    __shared__ short sA[64][72];
    __shared__ short sB[128][72];
    __shared__ short sT2[64][136];
    __shared__ short sB2[256][72];
    const int bm = blockIdx.x * 64;
    const int tid = threadIdx.x;
    const int lane = tid & 63, wid = tid >> 6;
    const int wm = wid & 1, wn = wid >> 1;
    const int l15 = lane & 15, kg = lane >> 4;

    // phase A: T2[64][128] = leaky(Z @ Wc2a + ba), K=64
#pragma unroll
    for (int it = 0; it < 2; ++it) {
        int idx = tid + it * 256;
        int r = idx >> 3, s = idx & 7;
        int gm = bm + r;
        uint4 va = {0u, 0u, 0u, 0u};
        if (gm < M) va = *(const uint4*)(Z + (size_t)gm * 64 + s * 8);
        *(uint4*)(&sA[r][s * 8]) = va;
    }
#pragma unroll
    for (int it = 0; it < 4; ++it) {
        int idx = tid + it * 256;
        int r = idx >> 3, s = idx & 7;
        *(uint4*)(&sB[r][s * 8]) = *(const uint4*)(Wa + r * 64 + s * 8);
    }
    __syncthreads();
    f32x4 accA[2][4];
#pragma unroll
    for (int i = 0; i < 2; i++)
#pragma unroll
        for (int j = 0; j < 4; j++) accA[i][j] = (f32x4){0.f, 0.f, 0.f, 0.f};
#pragma unroll
    for (int ks = 0; ks < 2; ++ks) {
        bf16x8 a[2], b[4];
#pragma unroll
        for (int i = 0; i < 2; i++)
            a[i] = *(const bf16x8*)(&sA[wm * 32 + i * 16 + l15][kg * 8 + ks * 32]);
#pragma unroll
        for (int j = 0; j < 4; j++)
            b[j] = *(const bf16x8*)(&sB[wn * 64 + j * 16 + l15][kg * 8 + ks * 32]);
#pragma unroll
        for (int i = 0; i < 2; i++)
#pragma unroll
            for (int j = 0; j < 4; j++)
                accA[i][j] = __builtin_amdgcn_mfma_f32_16x16x32_bf16(a[i], b[j], accA[i][j], 0, 0, 0);
    }
    __syncthreads();
#pragma unroll
    for (int i = 0; i < 2; i++) {
        int row0 = wm * 32 + i * 16 + kg * 4;
#pragma unroll
        for (int j = 0; j < 4; j++) {
            int col = wn * 64 + j * 16 + l15;
            float bv = ba[col];
#pragma unroll
            for (int r = 0; r < 4; r++)
                sT2[row0 + r][col] = f2bf(leaky_f(accA[i][j][r] + bv));
        }
    }
    __syncthreads();

    // phase B: H2[64][256] = leaky(T2 @ Wc2b + bb), K=128
    f32x4 accB[2][8];
#pragma unroll
    for (int i = 0; i < 2; i++)
#pragma unroll
        for (int j = 0; j < 8; j++) accB[i][j] = (f32x4){0.f, 0.f, 0.f, 0.f};
    for (int k0 = 0; k0 < 128; k0 += 64) {
#pragma unroll
        for (int it = 0; it < 8; ++it) {
            int idx = tid + it * 256;
            int r = idx >> 3, s = idx & 7;
            *(uint4*)(&sB2[r][s * 8]) = *(const uint4*)(Wb + r * 128 + k0 + s * 8);
        }
        __syncthreads();
#pragma unroll
        for (int ks = 0; ks < 2; ++ks) {
            bf16x8 a[2], b[8];
#pragma unroll
            for (int i = 0; i < 2; i++)
                a[i] = *(const bf16x8*)(&sT2[wm * 32 + i * 16 + l15][k0 + ks * 32 + kg * 8]);
#pragma unroll
            for (int j = 0; j < 8; j++)
                b[j] = *(const bf16x8*)(&sB2[wn * 128 + j * 16 + l15][kg * 8 + ks * 32]);
#pragma unroll
            for (int i = 0; i < 2; i++)
#pragma unroll
                for (int j = 0; j < 8; j++)
                    accB[i][j] = __builtin_amdgcn_mfma_f32_16x16x32_bf16(a[i], b[j], accB[i][j], 0, 0, 0);
        }
        __syncthreads();
    }
#pragma unroll
    for (int i = 0; i < 2; i++) {
        int row0 = wm * 32 + i * 16 + kg * 4;
#pragma unroll
        for (int j = 0; j < 8; j++) {
            int col = wn * 128 + j * 16 + l15;
            float bv = bb[col];
#pragma unroll
            for (int r = 0; r < 4; r++) {
                int grow = bm + row0 + r;
                if (grow < M)
                    H2[(size_t)grow * 256 + col] = f2bf(leaky_f(accB[i][j][r] + bv));
            }
        }
    }
}

// ---------------- S split-K MFMA ----------------
__global__ __launch_bounds__(256)
void sgemm_sk(const unsigned short* __restrict__ Zt, const unsigned short* __restrict__ MBt,
              float* __restrict__ part) {
    __shared__ short sA[64][72];
    __shared__ short sB[64][72];
    const int bn = blockIdx.x * 64;
    const int kc = blockIdx.y;
    const int tid = threadIdx.x;
    const int lane = tid & 63, wid = tid >> 6;
    const int wm = wid & 1, wn = wid >> 1;
    const int l15 = lane & 15, kg = lane >> 4;

    f32x4 acc[2][2];
#pragma unroll
    for (int i = 0; i < 2; i++)
#pragma unroll
        for (int j = 0; j < 2; j++) acc[i][j] = (f32x4){0.f, 0.f, 0.f, 0.f};

    for (int kk = 0; kk < 4; ++kk) {
        int k0 = kc * 256 + kk * 64;
#pragma unroll
        for (int it = 0; it < 2; ++it) {
            int idx = tid + it * 256;
            int r = idx >> 3, s = idx & 7;
            *(uint4*)(&sA[r][s * 8]) = *(const uint4*)(Zt + (size_t)r * KPAD + k0 + s * 8);
            *(uint4*)(&sB[r][s * 8]) = *(const uint4*)(MBt + (size_t)(bn + r) * KPAD + k0 + s * 8);
        }
        __syncthreads();
        bf16x8 a[2][2], b[2][2];
#pragma unroll
        for (int i = 0; i < 2; i++)
#pragma unroll
            for (int ks = 0; ks < 2; ++ks) {
                a[i][ks] = *(const bf16x8*)(&sA[wm * 32 + i * 16 + l15][kg * 8 + ks * 32]);
                b[i][ks] = *(const bf16x8*)(&sB[wn * 32 + i * 16 + l15][kg * 8 + ks * 32]);
            }
#pragma unroll
        for (int ks = 0; ks < 2; ++ks)
#pragma unroll
            for (int i = 0; i < 2; i++)
#pragma unroll
                for (int j = 0; j < 2; j++)
                    acc[i][j] = __builtin_amdgcn_mfma_f32_16x16x32_bf16(a[i][ks], b[j][ks], acc[i][j], 0, 0, 0);
        __syncthreads();
    }
#pragma unroll
    for (int i = 0; i < 2; i++) {
        int row0 = wm * 32 + i * 16 + kg * 4;
#pragma unroll
        for (int j = 0; j < 2; j++) {
            int col = bn + wn * 32 + j * 16 + l15;
#pragma unroll
            for (int r = 0; r < 4; r++)
                part[((size_t)kc * 64 + row0 + r) * 512 + col] = acc[i][j][r];
        }
    }
}

__global__ void reduce_S(const float* __restrict__ part, unsigned short* __restrict__ Stb) {
    int i = blockIdx.x * blockDim.x + threadIdx.x;
    if (i < 64 * 512) {
        float s = 0.f;
#pragma unroll
        for (int c = 0; c < 40; ++c) s += part[(size_t)c * (64 * 512) + i];
        int k = i >> 9, n = i & 511;
        Stb[(size_t)n * 64 + k] = f2bf(s);
    }
}

// ---------------- launch ----------------
extern "C" void kernel_launch(void* const* d_in, const int* in_sizes, int n_in,
                              void* d_out, int out_size, void* d_ws, size_t ws_size,
                              hipStream_t stream) {
    const float* x    = (const float*)d_in[0];
    const int*   rows = (const int*)d_in[1];
    const int*   cols = (const int*)d_in[2];
    const float* vals = (const float*)d_in[3];
    const float* W1   = (const float*)d_in[4];
    const float* b1   = (const float*)d_in[5];
    const float* Wc1a = (const float*)d_in[6];
    const float* bc1a = (const float*)d_in[7];
    const float* Wc1b = (const float*)d_in[8];
    const float* bc1b = (const float*)d_in[9];
    const float* Wc2a = (const float*)d_in[10];
    const float* bc2a = (const float*)d_in[11];
    const float* Wc2b = (const float*)d_in[12];
    const float* bc2b = (const float*)d_in[13];
    const float* W6   = (const float*)d_in[14];
    const float* b6   = (const float*)d_in[15];

    const int N = NROWS;
    const int E = in_sizes[1];

    float* ws = (float*)d_ws;
    unsigned short* XHI  = (unsigned short*)(ws + 0);         // [10000][512]
    unsigned short* C1b  = (unsigned short*)(ws + 2560000);   // [10000][256]
    unsigned short* HHI  = (unsigned short*)(ws + 3840000);   // [10000][256]; H2 aliases
    unsigned short* ZHI  = (unsigned short*)(ws + 5120000);   // [10000][64]
    unsigned short* ZT   = (unsigned short*)(ws + 5440000);   // [64][10240]
    unsigned short* MBt  = (unsigned short*)(ws + 5767680);   // [512][10240]
    float*          PART = ws + 8389120;                      // [40][64][512]
    unsigned short* STB  = (unsigned short*)(ws + 9699840);   // [512][64]
    unsigned short* W1T   = (unsigned short*)(ws + 9716224);  // [256][512]
    unsigned short* WC1AT = (unsigned short*)(ws + 9781760);  // [128][256]
    unsigned short* WC1BT = (unsigned short*)(ws + 9798144);  // [64][128]
    unsigned short* WC2AT = (unsigned short*)(ws + 9802240);  // [128][64]
    unsigned short* WC2BT = (unsigned short*)(ws + 9806336);  // [256][128]
    unsigned short* W6T   = (unsigned short*)(ws + 9822720);  // [512][256]
    unsigned short* H2HI  = HHI;

    int*   counts = (int*)(ws + 9888256);
    int*   starts = counts + 10000;
    int*   cursor = starts + 10001;
    int*   cols_s = cursor + 10000;
    float* vals_s = (float*)(cols_s + 320000);

    float* Out = (float*)d_out;
    float* Zp  = (float*)d_out + 5120000;

    const int GX = (N + 63) / 64;  // 157

    conv_all<<<6924, 256, 0, stream>>>(x, W1, Wc1a, Wc1b, Wc2a, Wc2b, W6, XHI,
                                       W1T, WC1AT, WC1BT, WC2AT, WC2BT, W6T,
                                       counts, ZT, MBt);

    hist_kernel<<<(E + 255) / 256, 256, 0, stream>>>(rows, counts, E);
    scan_kernel<<<1, 1024, 0, stream>>>(counts, starts, cursor, N);
    scatter_kernel<<<(E + 255) / 256, 256, 0, stream>>>(rows, cols, vals, cursor, cols_s, vals_s, E);

    // C1 = x @ W1 -> bf16
    gemm_mfma<0,0,1,0><<<dim3(GX, 4), 256, 0, stream>>>(XHI, W1T, nullptr,
                                                        nullptr, C1b, nullptr, 0, N, 256, 512);
    // H = leaky(spmm + b1) -> bf16
    spmm_leaky_kernel<<<N, 64, 0, stream>>>(starts, cols_s, vals_s, C1b, b1, HHI);

    // z = leaky(H@Wc1a+b)@Wc1b + b -> Zp f32, ZHI bf16, ZT bf16
    fused_enc<<<GX, 256, 0, stream>>>(HHI, WC1AT, WC1BT, bc1a, bc1b, Zp, ZHI, ZT, N);

    // H2 = leaky(leaky(z@Wc2a+b)@Wc2b + b) -> bf16 (aliases H)
    fused_dec<<<GX, 256, 0, stream>>>(ZHI, WC2AT, WC2BT, bc2a, bc2b, H2HI, N);

    // MBt = (H2 @ W6)^T -> bf16 [512][KPAD]
    gemm_mfma<0,0,0,1><<<dim3(GX, 8), 256, 0, stream>>>(H2HI, W6T, nullptr,
                                                        nullptr, nullptr, MBt, KPAD, N, 512, 256);
    // S = ZT @ MBt^T (split-K MFMA) -> PART -> STB [512][64]
    sgemm_sk<<<dim3(8, 40), 256, 0, stream>>>(ZT, MBt, PART);
    reduce_S<<<128, 256, 0, stream>>>(PART, STB);

    // out = z @ S + b6
    gemm_mfma<0,1,0,0><<<dim3(GX, 8), 256, 0, stream>>>(ZHI, STB, b6,
                                                        Out, nullptr, nullptr, 0, N, 512, 64);
}

// Round 7
// 135.589 us; speedup vs baseline: 3.7907x; 1.1717x over previous
//
#include <hip/hip_runtime.h>
#include <hip/hip_bf16.h>

#define NROWS 10000
#define KPAD  10240

typedef __attribute__((ext_vector_type(8))) short bf16x8;
typedef __attribute__((ext_vector_type(4))) float f32x4;

__device__ __forceinline__ float leaky_f(float x) { return x >= 0.f ? x : 0.01f * x; }

__device__ __forceinline__ unsigned short f2bf(float f) {
    union { float f; unsigned int u; } v; v.f = f;
    unsigned int r = v.u + 0x7fffu + ((v.u >> 16) & 1u);
    return (unsigned short)(r >> 16);
}
__device__ __forceinline__ float bf2f(unsigned short h) {
    union { unsigned int u; float f; } v; v.u = ((unsigned int)h) << 16;
    return v.f;
}

// ---------------- merged conversions + zero-init ----------------
// ranges: x-conv(uint4) | 6 weight transposes | counts=0 | ZT tail=0 | H2T tail=0
__global__ void conv_all(const float* __restrict__ x, const float* __restrict__ W1,
                         const float* __restrict__ Wc1a, const float* __restrict__ Wc1b,
                         const float* __restrict__ Wc2a, const float* __restrict__ Wc2b,
                         const float* __restrict__ W6,
                         unsigned short* __restrict__ XHI,
                         unsigned short* __restrict__ o1, unsigned short* __restrict__ o2,
                         unsigned short* __restrict__ o3, unsigned short* __restrict__ o4,
                         unsigned short* __restrict__ o5, unsigned short* __restrict__ o6,
                         int* __restrict__ counts, unsigned short* __restrict__ Zt,
                         unsigned short* __restrict__ H2t) {
    int gid = blockIdx.x * 256 + threadIdx.x;
    if (gid < 1280000) {
        float4 v = ((const float4*)x)[gid];
        ushort4 h;
        h.x = f2bf(v.x); h.y = f2bf(v.y); h.z = f2bf(v.z); h.w = f2bf(v.w);
        ((ushort4*)XHI)[gid] = h;
    } else if (gid < 1411072) {           // W1 512x256
        int i = gid - 1280000, k = i >> 8, n = i & 255;
        o1[n * 512 + k] = f2bf(W1[i]);
    } else if (gid < 1443840) {           // Wc1a 256x128
        int i = gid - 1411072, k = i >> 7, n = i & 127;
        o2[n * 256 + k] = f2bf(Wc1a[i]);
    } else if (gid < 1452032) {           // Wc1b 128x64
        int i = gid - 1443840, k = i >> 6, n = i & 63;
        o3[n * 128 + k] = f2bf(Wc1b[i]);
    } else if (gid < 1460224) {           // Wc2a 64x128
        int i = gid - 1452032, k = i >> 7, n = i & 127;
        o4[n * 64 + k] = f2bf(Wc2a[i]);
    } else if (gid < 1492992) {           // Wc2b 128x256
        int i = gid - 1460224, k = i >> 8, n = i & 255;
        o5[n * 128 + k] = f2bf(Wc2b[i]);
    } else if (gid < 1624064) {           // W6 256x512
        int i = gid - 1492992, k = i >> 9, n = i & 511;
        o6[n * 256 + k] = f2bf(W6[i]);
    } else if (gid < 1634064) {
        counts[gid - 1624064] = 0;
    } else if (gid < 1649424) {           // ZT pad tail [64][10000..10240)
        int i = gid - 1634064;
        Zt[(size_t)(i / 240) * KPAD + 10000 + (i % 240)] = 0;
    } else if (gid < 1710864) {           // H2T pad tail [256][10000..10240)
        int i = gid - 1649424;
        H2t[(size_t)(i / 240) * KPAD + 10000 + (i % 240)] = 0;
    }
}

// ---------------- CSR build ----------------
__global__ void hist_kernel(const int* __restrict__ rows, int* __restrict__ counts, int E) {
    int i = blockIdx.x * blockDim.x + threadIdx.x;
    if (i < E) atomicAdd(&counts[rows[i]], 1);
}

// thread-serial-10 + single 1024-scan (20 barriers instead of 200)
__global__ __launch_bounds__(1024)
void scan_kernel(const int* __restrict__ counts, int* __restrict__ starts,
                 int* __restrict__ cursor, int n) {
    __shared__ int buf[1024];
    int tid = threadIdx.x;
    int base = tid * 10;
    int v[10];
    int local = 0;
#pragma unroll
    for (int j = 0; j < 10; ++j) {
        int i = base + j;
        v[j] = (i < n) ? counts[i] : 0;
        local += v[j];
    }
    buf[tid] = local;
    __syncthreads();
    for (int off = 1; off < 1024; off <<= 1) {
        int t = (tid >= off) ? buf[tid - off] : 0;
        __syncthreads();
        buf[tid] += t;
        __syncthreads();
    }
    int run = buf[tid] - local;   // exclusive base for this thread's chunk
#pragma unroll
    for (int j = 0; j < 10; ++j) {
        int i = base + j;
        if (i < n) { starts[i] = run; cursor[i] = run; run += v[j]; }
    }
    if (tid == 1023) starts[n] = buf[1023];
}

__global__ void scatter_kernel(const int* __restrict__ rows, const int* __restrict__ cols,
                               const float* __restrict__ vals, int* __restrict__ cursor,
                               int* __restrict__ cols_s, float* __restrict__ vals_s, int E) {
    int i = blockIdx.x * blockDim.x + threadIdx.x;
    if (i < E) {
        int pos = atomicAdd(&cursor[rows[i]], 1);
        cols_s[pos] = cols[i];
        vals_s[pos] = vals[i];
    }
}

// ---------------- SpMM: H = leaky(A_sp @ C1 + b1), bf16 gather, unroll 4 ----------------
__global__ __launch_bounds__(64)
void spmm_leaky_kernel(const int* __restrict__ starts, const int* __restrict__ cols_s,
                       const float* __restrict__ vals_s, const unsigned short* __restrict__ C1b,
                       const float* __restrict__ b1, unsigned short* __restrict__ Hb) {
    int r = blockIdx.x;
    int t = threadIdx.x;
    float4 a0 = ((const float4*)b1)[t];
    float4 a1 = {0.f, 0.f, 0.f, 0.f};
    float4 a2 = {0.f, 0.f, 0.f, 0.f};
    float4 a3 = {0.f, 0.f, 0.f, 0.f};
    int s = starts[r], e = starts[r + 1];
    int p = s;
    for (; p + 4 <= e; p += 4) {
        int c0 = cols_s[p], c1 = cols_s[p + 1], c2 = cols_s[p + 2], c3 = cols_s[p + 3];
        float v0 = vals_s[p], v1 = vals_s[p + 1], v2 = vals_s[p + 2], v3 = vals_s[p + 3];
        ushort4 s0 = ((const ushort4*)(C1b + (size_t)c0 * 256))[t];
        ushort4 s1 = ((const ushort4*)(C1b + (size_t)c1 * 256))[t];
        ushort4 s2 = ((const ushort4*)(C1b + (size_t)c2 * 256))[t];
        ushort4 s3 = ((const ushort4*)(C1b + (size_t)c3 * 256))[t];
        a0.x += v0 * bf2f(s0.x); a0.y += v0 * bf2f(s0.y);
        a0.z += v0 * bf2f(s0.z); a0.w += v0 * bf2f(s0.w);
        a1.x += v1 * bf2f(s1.x); a1.y += v1 * bf2f(s1.y);
        a1.z += v1 * bf2f(s1.z); a1.w += v1 * bf2f(s1.w);
        a2.x += v2 * bf2f(s2.x); a2.y += v2 * bf2f(s2.y);
        a2.z += v2 * bf2f(s2.z); a2.w += v2 * bf2f(s2.w);
        a3.x += v3 * bf2f(s3.x); a3.y += v3 * bf2f(s3.y);
        a3.z += v3 * bf2f(s3.z); a3.w += v3 * bf2f(s3.w);
    }
    for (; p < e; ++p) {
        int c0 = cols_s[p];
        float v0 = vals_s[p];
        ushort4 s0 = ((const ushort4*)(C1b + (size_t)c0 * 256))[t];
        a0.x += v0 * bf2f(s0.x); a0.y += v0 * bf2f(s0.y);
        a0.z += v0 * bf2f(s0.z); a0.w += v0 * bf2f(s0.w);
    }
    ushort4 h;
    h.x = f2bf(leaky_f(a0.x + a1.x + a2.x + a3.x));
    h.y = f2bf(leaky_f(a0.y + a1.y + a2.y + a3.y));
    h.z = f2bf(leaky_f(a0.z + a1.z + a2.z + a3.z));
    h.w = f2bf(leaky_f(a0.w + a1.w + a2.w + a3.w));
    ((ushort4*)Hb)[(size_t)r * 64 + t] = h;
}

// ---------------- generic MFMA bf16 GEMM ----------------
template<int ACT, int WF32, int WBF, int WTB>
__global__ __launch_bounds__(256)
void gemm_mfma(const unsigned short* __restrict__ A, const unsigned short* __restrict__ Bt,
               const float* __restrict__ bias, float* __restrict__ Cf,
               unsigned short* __restrict__ Cb, unsigned short* __restrict__ Ct,
               int ldt, int M, int N, int K) {
    __shared__ short sA[64][72];
    __shared__ short sB[64][72];
    const int bm = blockIdx.x * 64;
    const int bn = blockIdx.y * 64;
    const int tid = threadIdx.x;
    const int lane = tid & 63, wid = tid >> 6;
    const int wm = wid & 1, wn = wid >> 1;
    const int l15 = lane & 15, kg = lane >> 4;

    f32x4 acc[2][2];
#pragma unroll
    for (int i = 0; i < 2; i++)
#pragma unroll
        for (int j = 0; j < 2; j++) acc[i][j] = (f32x4){0.f, 0.f, 0.f, 0.f};

    for (int k0 = 0; k0 < K; k0 += 64) {
#pragma unroll
        for (int it = 0; it < 2; ++it) {
            int idx = tid + it * 256;
            int r = idx >> 3, s = idx & 7;
            int gm = bm + r;
            uint4 va = {0u, 0u, 0u, 0u};
            if (gm < M) va = *(const uint4*)(A + (size_t)gm * K + k0 + s * 8);
            *(uint4*)(&sA[r][s * 8]) = va;
            uint4 vb = *(const uint4*)(Bt + (size_t)(bn + r) * K + k0 + s * 8);
            *(uint4*)(&sB[r][s * 8]) = vb;
        }
        __syncthreads();
        bf16x8 a[2][2], b[2][2];
#pragma unroll
        for (int i = 0; i < 2; i++)
#pragma unroll
            for (int ks = 0; ks < 2; ++ks) {
                a[i][ks] = *(const bf16x8*)(&sA[wm * 32 + i * 16 + l15][kg * 8 + ks * 32]);
                b[i][ks] = *(const bf16x8*)(&sB[wn * 32 + i * 16 + l15][kg * 8 + ks * 32]);
            }
#pragma unroll
        for (int ks = 0; ks < 2; ++ks)
#pragma unroll
            for (int i = 0; i < 2; i++)
#pragma unroll
                for (int j = 0; j < 2; j++)
                    acc[i][j] = __builtin_amdgcn_mfma_f32_16x16x32_bf16(a[i][ks], b[j][ks], acc[i][j], 0, 0, 0);
        __syncthreads();
    }

#pragma unroll
    for (int i = 0; i < 2; i++) {
        int row0 = wm * 32 + i * 16 + kg * 4;
#pragma unroll
        for (int j = 0; j < 2; j++) {
            int col = bn + wn * 32 + j * 16 + l15;
            float bv = bias ? bias[col] : 0.f;
            ushort4 tw;
#pragma unroll
            for (int r = 0; r < 4; r++) {
                int grow = bm + row0 + r;
                float v = acc[i][j][r] + bv;
                if (ACT) v = leaky_f(v);
                if (WF32) { if (grow < M) Cf[(size_t)grow * N + col] = v; }
                if (WBF)  { if (grow < M) Cb[(size_t)grow * N + col] = f2bf(v); }
                if (WTB)  ((unsigned short*)&tw)[r] = f2bf(v);
            }
            if (WTB && (bm + row0) < M)
                *(ushort4*)(&Ct[(size_t)col * ldt + bm + row0]) = tw;
        }
    }
}

// ---------------- fused encoder tail: H -> T1 (LDS) -> z ----------------
__global__ __launch_bounds__(256)
void fused_enc(const unsigned short* __restrict__ H,   // [M][256]
               const unsigned short* __restrict__ Wa,  // [128][256]
               const unsigned short* __restrict__ Wb,  // [64][128]
               const float* __restrict__ ba, const float* __restrict__ bb,
               float* __restrict__ Zf, unsigned short* __restrict__ Zb,
               unsigned short* __restrict__ Zt, int M) {
    __shared__ short sA[64][72];
    __shared__ short sB[128][72];
    __shared__ short sT1[64][136];
    __shared__ short sWb[64][136];
    const int bm = blockIdx.x * 64;
    const int tid = threadIdx.x;
    const int lane = tid & 63, wid = tid >> 6;
    const int wm = wid & 1, wn = wid >> 1;
    const int l15 = lane & 15, kg = lane >> 4;

    // stage Wc1b whole (64x128 = 1024 uint4)
#pragma unroll
    for (int it = 0; it < 4; ++it) {
        int idx = tid + it * 256;
        int r = idx >> 4, s = idx & 15;
        *(uint4*)(&sWb[r][s * 8]) = *(const uint4*)(Wb + r * 128 + s * 8);
    }

    // phase A: T1[64][128] = leaky(H @ Wc1a + ba)
    f32x4 accA[2][4];
#pragma unroll
    for (int i = 0; i < 2; i++)
#pragma unroll
        for (int j = 0; j < 4; j++) accA[i][j] = (f32x4){0.f, 0.f, 0.f, 0.f};

    for (int k0 = 0; k0 < 256; k0 += 64) {
#pragma unroll
        for (int it = 0; it < 2; ++it) {
            int idx = tid + it * 256;
            int r = idx >> 3, s = idx & 7;
            int gm = bm + r;
            uint4 va = {0u, 0u, 0u, 0u};
            if (gm < M) va = *(const uint4*)(H + (size_t)gm * 256 + k0 + s * 8);
            *(uint4*)(&sA[r][s * 8]) = va;
        }
#pragma unroll
        for (int it = 0; it < 4; ++it) {
            int idx = tid + it * 256;
            int r = idx >> 3, s = idx & 7;
            *(uint4*)(&sB[r][s * 8]) = *(const uint4*)(Wa + r * 256 + k0 + s * 8);
        }
        __syncthreads();
#pragma unroll
        for (int ks = 0; ks < 2; ++ks) {
            bf16x8 a[2], b[4];
#pragma unroll
            for (int i = 0; i < 2; i++)
                a[i] = *(const bf16x8*)(&sA[wm * 32 + i * 16 + l15][kg * 8 + ks * 32]);
#pragma unroll
            for (int j = 0; j < 4; j++)
                b[j] = *(const bf16x8*)(&sB[wn * 64 + j * 16 + l15][kg * 8 + ks * 32]);
#pragma unroll
            for (int i = 0; i < 2; i++)
#pragma unroll
                for (int j = 0; j < 4; j++)
                    accA[i][j] = __builtin_amdgcn_mfma_f32_16x16x32_bf16(a[i], b[j], accA[i][j], 0, 0, 0);
        }
        __syncthreads();
    }
#pragma unroll
    for (int i = 0; i < 2; i++) {
        int row0 = wm * 32 + i * 16 + kg * 4;
#pragma unroll
        for (int j = 0; j < 4; j++) {
            int col = wn * 64 + j * 16 + l15;
            float bv = ba[col];
#pragma unroll
            for (int r = 0; r < 4; r++)
                sT1[row0 + r][col] = f2bf(leaky_f(accA[i][j][r] + bv));
        }
    }
    __syncthreads();

    // phase B: z[64][64] = T1 @ Wc1b + bb
    f32x4 accB[2][2];
#pragma unroll
    for (int i = 0; i < 2; i++)
#pragma unroll
        for (int j = 0; j < 2; j++) accB[i][j] = (f32x4){0.f, 0.f, 0.f, 0.f};
#pragma unroll
    for (int kc = 0; kc < 4; ++kc) {
        bf16x8 a[2], b[2];
#pragma unroll
        for (int i = 0; i < 2; i++)
            a[i] = *(const bf16x8*)(&sT1[wm * 32 + i * 16 + l15][kc * 32 + kg * 8]);
#pragma unroll
        for (int j = 0; j < 2; j++)
            b[j] = *(const bf16x8*)(&sWb[wn * 32 + j * 16 + l15][kc * 32 + kg * 8]);
#pragma unroll
        for (int i = 0; i < 2; i++)
#pragma unroll
            for (int j = 0; j < 2; j++)
                accB[i][j] = __builtin_amdgcn_mfma_f32_16x16x32_bf16(a[i], b[j], accB[i][j], 0, 0, 0);
    }
#pragma unroll
    for (int i = 0; i < 2; i++) {
        int row0 = wm * 32 + i * 16 + kg * 4;
#pragma unroll
        for (int j = 0; j < 2; j++) {
            int col = wn * 32 + j * 16 + l15;
            float bv = bb[col];
            ushort4 tw;
#pragma unroll
            for (int r = 0; r < 4; r++) {
                int grow = bm + row0 + r;
                float v = accB[i][j][r] + bv;
                if (grow < M) {
                    Zf[(size_t)grow * 64 + col] = v;
                    Zb[(size_t)grow * 64 + col] = f2bf(v);
                }
                ((unsigned short*)&tw)[r] = f2bf(v);
            }
            if ((bm + row0) < M)
                *(ushort4*)(&Zt[(size_t)col * KPAD + bm + row0]) = tw;
        }
    }
}

// ---------------- fused decoder head: z -> T2 (LDS) -> H2^T ----------------
__global__ __launch_bounds__(256)
void fused_dec(const unsigned short* __restrict__ Z,   // [M][64]
               const unsigned short* __restrict__ Wa,  // [128][64]
               const unsigned short* __restrict__ Wb,  // [256][128]
               const float* __restrict__ ba, const float* __restrict__ bb,
               unsigned short* __restrict__ H2t, int M) {
    __shared__ short sA[64][72];
    __shared__ short sB[128][72];
    __shared__ short sT2[64][136];
    __shared__ short sB2[256][72];
    const int bm = blockIdx.x * 64;
    const int tid = threadIdx.x;
    const int lane = tid & 63, wid = tid >> 6;
    const int wm = wid & 1, wn = wid >> 1;
    const int l15 = lane & 15, kg = lane >> 4;

    // phase A: T2[64][128] = leaky(Z @ Wc2a + ba), K=64
#pragma unroll
    for (int it = 0; it < 2; ++it) {
        int idx = tid + it * 256;
        int r = idx >> 3, s = idx & 7;
        int gm = bm + r;
        uint4 va = {0u, 0u, 0u, 0u};
        if (gm < M) va = *(const uint4*)(Z + (size_t)gm * 64 + s * 8);
        *(uint4*)(&sA[r][s * 8]) = va;
    }
#pragma unroll
    for (int it = 0; it < 4; ++it) {
        int idx = tid + it * 256;
        int r = idx >> 3, s = idx & 7;
        *(uint4*)(&sB[r][s * 8]) = *(const uint4*)(Wa + r * 64 + s * 8);
    }
    __syncthreads();
    f32x4 accA[2][4];
#pragma unroll
    for (int i = 0; i < 2; i++)
#pragma unroll
        for (int j = 0; j < 4; j++) accA[i][j] = (f32x4){0.f, 0.f, 0.f, 0.f};
#pragma unroll
    for (int ks = 0; ks < 2; ++ks) {
        bf16x8 a[2], b[4];
#pragma unroll
        for (int i = 0; i < 2; i++)
            a[i] = *(const bf16x8*)(&sA[wm * 32 + i * 16 + l15][kg * 8 + ks * 32]);
#pragma unroll
        for (int j = 0; j < 4; j++)
            b[j] = *(const bf16x8*)(&sB[wn * 64 + j * 16 + l15][kg * 8 + ks * 32]);
#pragma unroll
        for (int i = 0; i < 2; i++)
#pragma unroll
            for (int j = 0; j < 4; j++)
                accA[i][j] = __builtin_amdgcn_mfma_f32_16x16x32_bf16(a[i], b[j], accA[i][j], 0, 0, 0);
    }
    __syncthreads();
#pragma unroll
    for (int i = 0; i < 2; i++) {
        int row0 = wm * 32 + i * 16 + kg * 4;
#pragma unroll
        for (int j = 0; j < 4; j++) {
            int col = wn * 64 + j * 16 + l15;
            float bv = ba[col];
#pragma unroll
            for (int r = 0; r < 4; r++)
                sT2[row0 + r][col] = f2bf(leaky_f(accA[i][j][r] + bv));
        }
    }
    __syncthreads();

    // phase B: H2[64][256] = leaky(T2 @ Wc2b + bb), K=128 -> write transposed H2t[col][row]
    f32x4 accB[2][8];
#pragma unroll
    for (int i = 0; i < 2; i++)
#pragma unroll
        for (int j = 0; j < 8; j++) accB[i][j] = (f32x4){0.f, 0.f, 0.f, 0.f};
    for (int k0 = 0; k0 < 128; k0 += 64) {
#pragma unroll
        for (int it = 0; it < 8; ++it) {
            int idx = tid + it * 256;
            int r = idx >> 3, s = idx & 7;
            *(uint4*)(&sB2[r][s * 8]) = *(const uint4*)(Wb + r * 128 + k0 + s * 8);
        }
        __syncthreads();
#pragma unroll
        for (int ks = 0; ks < 2; ++ks) {
            bf16x8 a[2], b[8];
#pragma unroll
            for (int i = 0; i < 2; i++)
                a[i] = *(const bf16x8*)(&sT2[wm * 32 + i * 16 + l15][k0 + ks * 32 + kg * 8]);
#pragma unroll
            for (int j = 0; j < 8; j++)
                b[j] = *(const bf16x8*)(&sB2[wn * 128 + j * 16 + l15][kg * 8 + ks * 32]);
#pragma unroll
            for (int i = 0; i < 2; i++)
#pragma unroll
                for (int j = 0; j < 8; j++)
                    accB[i][j] = __builtin_amdgcn_mfma_f32_16x16x32_bf16(a[i], b[j], accB[i][j], 0, 0, 0);
        }
        __syncthreads();
    }
#pragma unroll
    for (int i = 0; i < 2; i++) {
        int row0 = wm * 32 + i * 16 + kg * 4;
#pragma unroll
        for (int j = 0; j < 8; j++) {
            int col = wn * 128 + j * 16 + l15;
            float bv = bb[col];
            ushort4 tw;
#pragma unroll
            for (int r = 0; r < 4; r++)
                ((unsigned short*)&tw)[r] = f2bf(leaky_f(accB[i][j][r] + bv));
            if ((bm + row0) < M)
                *(ushort4*)(&H2t[(size_t)col * KPAD + bm + row0]) = tw;
        }
    }
}

// ---------------- S2 split-K MFMA: S2_part = ZT @ H2t^T per K-chunk ----------------
// ZT [64][KPAD], H2t [256][KPAD]; grid (4 n-tiles, 40 splits of 256)
__global__ __launch_bounds__(256)
void sgemm_sk(const unsigned short* __restrict__ Zt, const unsigned short* __restrict__ H2t,
              float* __restrict__ part) {
    __shared__ short sA[64][72];
    __shared__ short sB[64][72];
    const int bn = blockIdx.x * 64;
    const int kc = blockIdx.y;
    const int tid = threadIdx.x;
    const int lane = tid & 63, wid = tid >> 6;
    const int wm = wid & 1, wn = wid >> 1;
    const int l15 = lane & 15, kg = lane >> 4;

    f32x4 acc[2][2];
#pragma unroll
    for (int i = 0; i < 2; i++)
#pragma unroll
        for (int j = 0; j < 2; j++) acc[i][j] = (f32x4){0.f, 0.f, 0.f, 0.f};

    for (int kk = 0; kk < 4; ++kk) {
        int k0 = kc * 256 + kk * 64;
#pragma unroll
        for (int it = 0; it < 2; ++it) {
            int idx = tid + it * 256;
            int r = idx >> 3, s = idx & 7;
            *(uint4*)(&sA[r][s * 8]) = *(const uint4*)(Zt + (size_t)r * KPAD + k0 + s * 8);
            *(uint4*)(&sB[r][s * 8]) = *(const uint4*)(H2t + (size_t)(bn + r) * KPAD + k0 + s * 8);
        }
        __syncthreads();
        bf16x8 a[2][2], b[2][2];
#pragma unroll
        for (int i = 0; i < 2; i++)
#pragma unroll
            for (int ks = 0; ks < 2; ++ks) {
                a[i][ks] = *(const bf16x8*)(&sA[wm * 32 + i * 16 + l15][kg * 8 + ks * 32]);
                b[i][ks] = *(const bf16x8*)(&sB[wn * 32 + i * 16 + l15][kg * 8 + ks * 32]);
            }
#pragma unroll
        for (int ks = 0; ks < 2; ++ks)
#pragma unroll
            for (int i = 0; i < 2; i++)
#pragma unroll
                for (int j = 0; j < 2; j++)
                    acc[i][j] = __builtin_amdgcn_mfma_f32_16x16x32_bf16(a[i][ks], b[j][ks], acc[i][j], 0, 0, 0);
        __syncthreads();
    }
#pragma unroll
    for (int i = 0; i < 2; i++) {
        int row0 = wm * 32 + i * 16 + kg * 4;
#pragma unroll
        for (int j = 0; j < 2; j++) {
            int col = bn + wn * 32 + j * 16 + l15;
#pragma unroll
            for (int r = 0; r < 4; r++)
                part[((size_t)kc * 64 + row0 + r) * 256 + col] = acc[i][j][r];
        }
    }
}

// reduce 40 partials -> S2 bf16 [64][256] row-major
__global__ void reduce_S2(const float* __restrict__ part, unsigned short* __restrict__ S2b) {
    int i = blockIdx.x * blockDim.x + threadIdx.x;
    if (i < 64 * 256) {
        float s = 0.f;
#pragma unroll
        for (int c = 0; c < 40; ++c) s += part[(size_t)c * (64 * 256) + i];
        S2b[i] = f2bf(s);
    }
}

// ---------------- launch ----------------
extern "C" void kernel_launch(void* const* d_in, const int* in_sizes, int n_in,
                              void* d_out, int out_size, void* d_ws, size_t ws_size,
                              hipStream_t stream) {
    const float* x    = (const float*)d_in[0];
    const int*   rows = (const int*)d_in[1];
    const int*   cols = (const int*)d_in[2];
    const float* vals = (const float*)d_in[3];
    const float* W1   = (const float*)d_in[4];
    const float* b1   = (const float*)d_in[5];
    const float* Wc1a = (const float*)d_in[6];
    const float* bc1a = (const float*)d_in[7];
    const float* Wc1b = (const float*)d_in[8];
    const float* bc1b = (const float*)d_in[9];
    const float* Wc2a = (const float*)d_in[10];
    const float* bc2a = (const float*)d_in[11];
    const float* Wc2b = (const float*)d_in[12];
    const float* bc2b = (const float*)d_in[13];
    const float* W6   = (const float*)d_in[14];
    const float* b6   = (const float*)d_in[15];

    const int N = NROWS;
    const int E = in_sizes[1];

    float* ws = (float*)d_ws;
    unsigned short* XHI  = (unsigned short*)(ws + 0);         // [10000][512]
    unsigned short* C1b  = (unsigned short*)(ws + 2560000);   // [10000][256]
    unsigned short* HHI  = (unsigned short*)(ws + 3840000);   // [10000][256]
    unsigned short* ZHI  = (unsigned short*)(ws + 5120000);   // [10000][64]
    unsigned short* ZT   = (unsigned short*)(ws + 5440000);   // [64][10240]
    unsigned short* H2T  = (unsigned short*)(ws + 5767680);   // [256][10240]
    float*          PART = ws + 7078400;                      // [40][64][256]
    unsigned short* S2B  = (unsigned short*)(ws + 7733760);   // [64][256]
    unsigned short* W6ST = (unsigned short*)(ws + 7741952);   // [512][64]
    unsigned short* W1T   = (unsigned short*)(ws + 7758336);  // [256][512]
    unsigned short* WC1AT = (unsigned short*)(ws + 7823872);  // [128][256]
    unsigned short* WC1BT = (unsigned short*)(ws + 7840256);  // [64][128]
    unsigned short* WC2AT = (unsigned short*)(ws + 7844352);  // [128][64]
    unsigned short* WC2BT = (unsigned short*)(ws + 7848448);  // [256][128]
    unsigned short* W6T   = (unsigned short*)(ws + 7864832);  // [512][256]

    int*   counts = (int*)(ws + 7930368);
    int*   starts = counts + 10000;
    int*   cursor = starts + 10001;
    int*   cols_s = cursor + 10000;
    float* vals_s = (float*)(cols_s + 320000);   // ends ~8.59M floats = 34.4 MB

    float* Out = (float*)d_out;
    float* Zp  = (float*)d_out + 5120000;

    const int GX = (N + 63) / 64;  // 157

    conv_all<<<6683, 256, 0, stream>>>(x, W1, Wc1a, Wc1b, Wc2a, Wc2b, W6, XHI,
                                       W1T, WC1AT, WC1BT, WC2AT, WC2BT, W6T,
                                       counts, ZT, H2T);

    hist_kernel<<<(E + 255) / 256, 256, 0, stream>>>(rows, counts, E);
    scan_kernel<<<1, 1024, 0, stream>>>(counts, starts, cursor, N);
    scatter_kernel<<<(E + 255) / 256, 256, 0, stream>>>(rows, cols, vals, cursor, cols_s, vals_s, E);

    // C1 = x @ W1 -> bf16
    gemm_mfma<0,0,1,0><<<dim3(GX, 4), 256, 0, stream>>>(XHI, W1T, nullptr,
                                                        nullptr, C1b, nullptr, 0, N, 256, 512);
    // H = leaky(spmm + b1) -> bf16
    spmm_leaky_kernel<<<N, 64, 0, stream>>>(starts, cols_s, vals_s, C1b, b1, HHI);

    // z = leaky(H@Wc1a+b)@Wc1b + b -> Zp f32, ZHI bf16, ZT bf16
    fused_enc<<<GX, 256, 0, stream>>>(HHI, WC1AT, WC1BT, bc1a, bc1b, Zp, ZHI, ZT, N);

    // H2^T = [leaky(leaky(z@Wc2a+b)@Wc2b + b)]^T -> bf16 [256][KPAD]
    fused_dec<<<GX, 256, 0, stream>>>(ZHI, WC2AT, WC2BT, bc2a, bc2b, H2T, N);

    // S2 = z^T @ H2 (split-K MFMA) -> PART -> S2B [64][256]
    sgemm_sk<<<dim3(4, 40), 256, 0, stream>>>(ZT, H2T, PART);
    reduce_S2<<<64, 256, 0, stream>>>(PART, S2B);

    // W6S = S2 @ W6 -> W6ST [512][64] bf16 (transposed epilogue)
    gemm_mfma<0,0,0,1><<<dim3(1, 8), 256, 0, stream>>>(S2B, W6T, nullptr,
                                                       nullptr, nullptr, W6ST, 64, 64, 512, 256);

    // out = z @ W6S + b6 -> f32
    gemm_mfma<0,1,0,0><<<dim3(GX, 8), 256, 0, stream>>>(ZHI, W6ST, b6,
                                                        Out, nullptr, nullptr, 0, N, 512, 64);
}